// Round 4
// baseline (215.263 us; speedup 1.0000x reference)
//
#include <hip/hip_runtime.h>

typedef unsigned short u16;
typedef __attribute__((ext_vector_type(8))) short short8;
typedef __attribute__((ext_vector_type(4))) float floatx4;

__device__ __forceinline__ u16 f2bf(float x){
  union { float f; unsigned u; } v; v.f = x;
  unsigned r = v.u + 0x7fffu + ((v.u >> 16) & 1u);
  return (u16)(r >> 16);
}

__device__ __forceinline__ unsigned cvt_pk_bf16(float lo, float hi){
  unsigned r;
  asm("v_cvt_pk_bf16_f32 %0, %1, %2" : "=v"(r) : "v"(lo), "v"(hi));
  return r;
}

__device__ __forceinline__ void gld16(const u16* g, u16* l){
  __builtin_amdgcn_global_load_lds(
      (const __attribute__((address_space(1))) void*)g,
      (__attribute__((address_space(3))) void*)l, 16, 0, 0);
}

// ---------------- fused fp32 -> bf16 convert (x + 4 weights, one launch) -------
__global__ void k_cvt_all(const float* __restrict__ x,
                          const float* __restrict__ wq, const float* __restrict__ wk,
                          const float* __restrict__ wv, const float* __restrict__ wo,
                          u16* __restrict__ xb, u16* __restrict__ wqb, u16* __restrict__ wkb,
                          u16* __restrict__ wvb, u16* __restrict__ wob){
  const int i = blockIdx.x * 256 + threadIdx.x;   // float4 index, total 2097152
  const float* s; u16* d; int off;
  if (i < 1048576) { s = x; d = xb; off = i; }
  else {
    const int j = i - 1048576;
    const int wsel = j >> 18;          // 262144 f4 per weight
    off = j & 262143;
    s = (wsel==0) ? wq : (wsel==1) ? wk : (wsel==2) ? wv : wo;
    d = (wsel==0) ? wqb : (wsel==1) ? wkb : (wsel==2) ? wvb : wob;
  }
  const float4 f = ((const float4*)s)[off];
  unsigned lo = (unsigned)f2bf(f.x) | ((unsigned)f2bf(f.y) << 16);
  unsigned hi = (unsigned)f2bf(f.z) | ((unsigned)f2bf(f.w) << 16);
  ((uint2*)d)[off] = make_uint2(lo, hi);
}

// ---------------- GEMM: C[4096][1024] = A[4096][1024] * W[1024][1024]^T + b --------
// mode 0: Q (bf16 out, [bh][s][64], *qscale)   mode 1: K (bf16, [bh][s][64])
// mode 2: V (bf16, [bh][64][s])                mode 3: fp32 out [4096][1024]
__global__ __launch_bounds__(256) void k_gemm(
    const u16* __restrict__ A,
    const u16* __restrict__ Wq, const u16* __restrict__ Wk, const u16* __restrict__ Wv,
    const float* __restrict__ bq, const float* __restrict__ bk, const float* __restrict__ bv,
    u16* __restrict__ Qo, u16* __restrict__ Ko, u16* __restrict__ Vo,
    float* __restrict__ Fo, int oproj)
{
  const int mode = oproj ? 3 : (int)blockIdx.z;
  const u16* W      = (mode==1) ? Wk : (mode==2) ? Wv : Wq;
  const float* bias = (mode==1) ? bk : (mode==2) ? bv : bq;

  __shared__ u16 lA[2][4096];   // [128 rows][32 k] bf16, k-groups-of-8 swizzled
  __shared__ u16 lB[2][4096];

  const int tid  = threadIdx.x;
  const int row0 = blockIdx.y * 128;
  const int col0 = blockIdx.x * 128;

  const int srow = tid >> 2;                    // 0..63
  const int sgp  = tid & 3;
  const int sgl  = sgp ^ ((srow >> 1) & 3);
  const u16* ga0 = A + (row0 + srow)      * 1024 + sgl * 8;
  const u16* ga1 = A + (row0 + srow + 64) * 1024 + sgl * 8;
  const u16* gb0 = W + (col0 + srow)      * 1024 + sgl * 8;
  const u16* gb1 = W + (col0 + srow + 64) * 1024 + sgl * 8;

  const int l  = tid & 63, w = tid >> 6;
  const int wr = w >> 1,  wc = w & 1;
  const int lr = l & 15,  grp = l >> 4;
  const int sw = (lr >> 1) & 3;
  int aoff[4], boff[4];
#pragma unroll
  for (int m = 0; m < 4; ++m) aoff[m] = (wr*64 + m*16 + lr)*32 + ((grp ^ sw) * 8);
#pragma unroll
  for (int n = 0; n < 4; ++n) boff[n] = (wc*64 + n*16 + lr)*32 + ((grp ^ sw) * 8);

  floatx4 acc[4][4];
#pragma unroll
  for (int m = 0; m < 4; ++m)
#pragma unroll
    for (int n = 0; n < 4; ++n) acc[m][n] = (floatx4){0.f, 0.f, 0.f, 0.f};

#define STAGE(buf, kt_) do { \
    const int k0_ = (kt_) * 32; \
    gld16(ga0 + k0_, &lA[(buf)][tid*8]); \
    gld16(ga1 + k0_, &lA[(buf)][2048 + tid*8]); \
    gld16(gb0 + k0_, &lB[(buf)][tid*8]); \
    gld16(gb1 + k0_, &lB[(buf)][2048 + tid*8]); \
  } while (0)

  STAGE(0, 0);
  __syncthreads();
  for (int kt = 0; kt < 32; ++kt) {
    const int cur = kt & 1;
    if (kt < 31) STAGE(cur ^ 1, kt + 1);
    short8 af[4], bf[4];
#pragma unroll
    for (int m = 0; m < 4; ++m) af[m] = *(const short8*)&lA[cur][aoff[m]];
#pragma unroll
    for (int n = 0; n < 4; ++n) bf[n] = *(const short8*)&lB[cur][boff[n]];
#pragma unroll
    for (int m = 0; m < 4; ++m)
#pragma unroll
      for (int n = 0; n < 4; ++n)
        acc[m][n] = __builtin_amdgcn_mfma_f32_16x16x32_bf16(af[m], bf[n], acc[m][n], 0, 0, 0);
    __syncthreads();
  }
#undef STAGE

  if (mode == 3) {
#pragma unroll
    for (int n = 0; n < 4; ++n) {
      const int cg = col0 + wc*64 + n*16 + lr;
      const float bb = bias[cg];
#pragma unroll
      for (int m = 0; m < 4; ++m) {
        const int rg = row0 + wr*64 + m*16 + grp*4;
#pragma unroll
        for (int j = 0; j < 4; ++j)
          Fo[(rg + j) * 1024 + cg] = acc[m][n][j] + bb;
      }
    }
  } else {
    const float sc = (mode == 0) ? 0.18033688011112042f : 1.0f;  // 0.125*log2(e) for Q
    u16* dst = (mode == 0) ? Qo : (mode == 1) ? Ko : Vo;
#pragma unroll
    for (int n = 0; n < 4; ++n) {
      const int cg = col0 + wc*64 + n*16 + lr;
      const float bb = bias[cg];
      const int h = cg >> 6, d = cg & 63;
#pragma unroll
      for (int m = 0; m < 4; ++m) {
#pragma unroll
        for (int j = 0; j < 4; ++j) {
          const int rg = row0 + wr*64 + m*16 + grp*4 + j;
          const int b = rg >> 11, s5 = rg & 2047;
          const float val = (acc[m][n][j] + bb) * sc;
          int idx;
          if (mode == 2) idx = ((b*16 + h)*64 + d)*2048 + s5;
          else           idx = ((b*16 + h)*2048 + s5)*64 + d;
          dst[idx] = f2bf(val);
        }
      }
    }
  }
}

// ---------------- flash attention v4: barrier-free, direct-L2 fragments ----------
// grid: 1024 blocks x 256 thr (4 independent waves). Each wave owns one 16-q chunk.
// Block's 4 waves = chunks {2rr, 127-2rr, 2rr+1, 126-2rr} of same bh -> 66 tiles/block.
// No __syncthreads. K/V fragments loaded global->reg (L2-resident via XCD grouping).
__global__ __launch_bounds__(256, 4) void k_attn(
    const u16* __restrict__ Q, const u16* __restrict__ K,
    const u16* __restrict__ V, u16* __restrict__ O)
{
  __shared__ u16 lP[4][1024];     // [wave][16 q][64 keys] group-swizzled (wave-private)

  const int tid = threadIdx.x;
  const int bid = (int)blockIdx.x;
  const int xcd = bid & 7, r = bid >> 3;       // 128 blocks per XCD
  const int bh = xcd * 4 + (r >> 5);           // 4 bh per XCD -> K/V L2-resident
  const int rr = r & 31;

  const int l = tid & 63, w = tid >> 6;
  const int lr = l & 15, grp = l >> 4;

  // chunk pairing: block total = 66 k-tiles regardless of rr (perfect balance)
  const int c = ((w & 1) == 0) ? (2*rr + (w >> 1)) : (127 - 2*rr - (w >> 1));
  const int qw0 = c * 16;
  const int nkt = (c >> 2) + 1;

  const u16* Qh = Q + (size_t)bh * 2048 * 64;
  const u16* Kh = K + (size_t)bh * 2048 * 64;
  const u16* Vh = V + (size_t)bh * 64 * 2048;

  // Q fragments (B-operand: lane holds Q[qw0+lr][kk*32+grp*8..+7])
  short8 qf[2];
#pragma unroll
  for (int kk = 0; kk < 2; ++kk)
    qf[kk] = *(const short8*)(Qh + (qw0 + lr)*64 + kk*32 + grp*8);

  floatx4 accO[4];                 // O^T: [d=dn*16+grp*4+j][q=lr]
  float mrow = -1e30f, lrow = 0.f;
#pragma unroll
  for (int dn = 0; dn < 4; ++dn) accO[dn] = (floatx4){0.f, 0.f, 0.f, 0.f};

  u16* lPw = &lP[w][0];
  const int swz = lr & 7;

  for (int kt = 0; kt < nkt; ++kt) {
    const int kb = kt * 64;

    // K fragments (A-operand): lane holds K[kb+n*16+lr][kk*32+grp*8..+7]
    // V^T fragments (A-operand): lane holds V^T[dn*16+lr][kb+kk*32+grp*8..+7]
    // Issue ALL loads up front: V-loads hide under QK^T + softmax.
    short8 kf[4][2], vf[4][2];
#pragma unroll
    for (int n = 0; n < 4; ++n)
#pragma unroll
      for (int kk = 0; kk < 2; ++kk)
        kf[n][kk] = *(const short8*)(Kh + (kb + n*16 + lr)*64 + kk*32 + grp*8);
#pragma unroll
    for (int dn = 0; dn < 4; ++dn)
#pragma unroll
      for (int kk = 0; kk < 2; ++kk)
        vf[dn][kk] = *(const short8*)(Vh + (dn*16 + lr)*2048 + kb + kk*32 + grp*8);

    // S^T = K Q^T : st[n] reg j -> key = kb+n*16+grp*4+j, query = qw0+lr
    floatx4 st[4];
#pragma unroll
    for (int n = 0; n < 4; ++n) st[n] = (floatx4){0.f, 0.f, 0.f, 0.f};
#pragma unroll
    for (int n = 0; n < 4; ++n)
#pragma unroll
      for (int kk = 0; kk < 2; ++kk)
        st[n] = __builtin_amdgcn_mfma_f32_16x16x32_bf16(kf[n][kk], qf[kk], st[n], 0, 0, 0);

    // causal mask (only final tile is partial)
    const int lim = qw0 + lr - kb;     // key offset <= lim is valid
    if (63 > lim) {
#pragma unroll
      for (int n = 0; n < 4; ++n)
#pragma unroll
        for (int j = 0; j < 4; ++j)
          if (n*16 + grp*4 + j > lim) st[n][j] = -1e30f;
    }

    // online softmax: per-lane scalar state, 2 shuffles per reduce
    float mt = st[0][0];
#pragma unroll
    for (int n = 0; n < 4; ++n)
#pragma unroll
      for (int j = 0; j < 4; ++j) mt = fmaxf(mt, st[n][j]);
    mt = fmaxf(mt, __shfl_xor(mt, 16));
    mt = fmaxf(mt, __shfl_xor(mt, 32));
    const float mn = fmaxf(mrow, mt);
    const float alpha = exp2f(mrow - mn);
    mrow = mn;
    float ps = 0.f;
#pragma unroll
    for (int n = 0; n < 4; ++n)
#pragma unroll
      for (int j = 0; j < 4; ++j) {
        const float p = exp2f(st[n][j] - mn);
        st[n][j] = p;
        ps += p;
      }
    ps += __shfl_xor(ps, 16);
    ps += __shfl_xor(ps, 32);
    lrow = lrow * alpha + ps;
#pragma unroll
    for (int dn = 0; dn < 4; ++dn) accO[dn] *= alpha;

    // pack P -> wave-private LDS [q][key], swizzled groups-of-8
#pragma unroll
    for (int n = 0; n < 4; ++n)
#pragma unroll
      for (int p2 = 0; p2 < 2; ++p2) {
        const unsigned pk = cvt_pk_bf16(st[n][2*p2], st[n][2*p2+1]);
        const int pg = (2*n + (grp >> 1)) ^ swz;
        ((unsigned*)lPw)[lr*32 + pg*4 + (grp & 1)*2 + p2] = pk;
      }

    asm volatile("s_waitcnt lgkmcnt(0)" ::: "memory");

    short8 pa[2];
#pragma unroll
    for (int kk = 0; kk < 2; ++kk)
      pa[kk] = *(const short8*)&lPw[lr*64 + (((kk*4 + grp) ^ swz) * 8)];

    // O^T += V^T P : accO[dn] reg j -> d = dn*16+grp*4+j, q = qw0+lr
#pragma unroll
    for (int dn = 0; dn < 4; ++dn)
#pragma unroll
      for (int kk = 0; kk < 2; ++kk)
        accO[dn] = __builtin_amdgcn_mfma_f32_16x16x32_bf16(vf[dn][kk], pa[kk], accO[dn], 0, 0, 0);
  }

  // epilogue: O[token][h*64+d] bf16, packed u32 stores
  const int b = bh >> 4, h = bh & 15;
  const float inv = 1.0f / lrow;
  const int token = b*2048 + qw0 + lr;
#pragma unroll
  for (int dn = 0; dn < 4; ++dn)
#pragma unroll
    for (int p2 = 0; p2 < 2; ++p2) {
      const unsigned pk = cvt_pk_bf16(accO[dn][2*p2] * inv, accO[dn][2*p2+1] * inv);
      *(unsigned*)&O[token*1024 + h*64 + dn*16 + grp*4 + 2*p2] = pk;
    }
}

// ---------------- launcher ----------------
extern "C" void kernel_launch(void* const* d_in, const int* in_sizes, int n_in,
                              void* d_out, int out_size, void* d_ws, size_t ws_size,
                              hipStream_t stream) {
  const float* x  = (const float*)d_in[0];
  const float* Wq = (const float*)d_in[1];
  const float* bq = (const float*)d_in[2];
  const float* Wk = (const float*)d_in[3];
  const float* bk = (const float*)d_in[4];
  const float* Wv = (const float*)d_in[5];
  const float* bv = (const float*)d_in[6];
  const float* Wo = (const float*)d_in[7];
  const float* bo = (const float*)d_in[8];
  float* out = (float*)d_out;

  char* ws = (char*)d_ws;
  u16* xb  = (u16*)(ws + 0);          // [4096][1024] bf16
  u16* wqb = (u16*)(ws + 8388608);
  u16* wkb = (u16*)(ws + 10485760);
  u16* wvb = (u16*)(ws + 12582912);
  u16* wob = (u16*)(ws + 14680064);
  u16* Qb  = (u16*)(ws + 16777216);   // [32][2048][64]
  u16* Kb  = (u16*)(ws + 25165824);   // [32][2048][64]
  u16* Vb  = (u16*)(ws + 33554432);   // [32][64][2048]
  u16* Ab  = (u16*)(ws + 41943040);   // [4096][1024]

  k_cvt_all<<<dim3(8192), 256, 0, stream>>>(x, Wq, Wk, Wv, Wo, xb, wqb, wkb, wvb, wob);

  k_gemm<<<dim3(8, 32, 3), 256, 0, stream>>>(xb, wqb, wkb, wvb, bq, bk, bv,
                                             Qb, Kb, Vb, nullptr, 0);

  k_attn<<<dim3(1024), 256, 0, stream>>>(Qb, Kb, Vb, Ab);

  k_gemm<<<dim3(8, 32, 1), 256, 0, stream>>>(Ab, wob, wob, wob, bo, bo, bo,
                                             nullptr, nullptr, nullptr, out, 1);
}

// Round 5
// 182.932 us; speedup vs baseline: 1.1767x; 1.1767x over previous
//
#include <hip/hip_runtime.h>

typedef unsigned short u16;
typedef __attribute__((ext_vector_type(8))) short short8;
typedef __attribute__((ext_vector_type(4))) float floatx4;

__device__ __forceinline__ u16 f2bf(float x){
  union { float f; unsigned u; } v; v.f = x;
  unsigned r = v.u + 0x7fffu + ((v.u >> 16) & 1u);
  return (u16)(r >> 16);
}

__device__ __forceinline__ unsigned cvt_pk_bf16(float lo, float hi){
  unsigned r;
  asm("v_cvt_pk_bf16_f32 %0, %1, %2" : "=v"(r) : "v"(lo), "v"(hi));
  return r;
}

__device__ __forceinline__ void gld16(const u16* g, u16* l){
  __builtin_amdgcn_global_load_lds(
      (const __attribute__((address_space(1))) void*)g,
      (__attribute__((address_space(3))) void*)l, 16, 0, 0);
}

// ---------------- fused fp32 -> bf16 convert (x + 4 weights, one launch) -------
__global__ void k_cvt_all(const float* __restrict__ x,
                          const float* __restrict__ wq, const float* __restrict__ wk,
                          const float* __restrict__ wv, const float* __restrict__ wo,
                          u16* __restrict__ xb, u16* __restrict__ wqb, u16* __restrict__ wkb,
                          u16* __restrict__ wvb, u16* __restrict__ wob){
  const int i = blockIdx.x * 256 + threadIdx.x;   // float4 index, total 2097152
  const float* s; u16* d; int off;
  if (i < 1048576) { s = x; d = xb; off = i; }
  else {
    const int j = i - 1048576;
    const int wsel = j >> 18;          // 262144 f4 per weight
    off = j & 262143;
    s = (wsel==0) ? wq : (wsel==1) ? wk : (wsel==2) ? wv : wo;
    d = (wsel==0) ? wqb : (wsel==1) ? wkb : (wsel==2) ? wvb : wob;
  }
  const float4 f = ((const float4*)s)[off];
  unsigned lo = (unsigned)f2bf(f.x) | ((unsigned)f2bf(f.y) << 16);
  unsigned hi = (unsigned)f2bf(f.z) | ((unsigned)f2bf(f.w) << 16);
  ((uint2*)d)[off] = make_uint2(lo, hi);
}

// ---------------- GEMM: C[4096][1024] = A[4096][1024] * W[1024][1024]^T + b --------
// mode 0: Q (bf16 out, [bh][s][64], *qscale)   mode 1: K (bf16, [bh][s][64])
// mode 2: V (bf16, [bh][64][s])                mode 3: fp32 out [4096][1024]
__global__ __launch_bounds__(256) void k_gemm(
    const u16* __restrict__ A,
    const u16* __restrict__ Wq, const u16* __restrict__ Wk, const u16* __restrict__ Wv,
    const float* __restrict__ bq, const float* __restrict__ bk, const float* __restrict__ bv,
    u16* __restrict__ Qo, u16* __restrict__ Ko, u16* __restrict__ Vo,
    float* __restrict__ Fo, int oproj)
{
  const int mode = oproj ? 3 : (int)blockIdx.z;
  const u16* W      = (mode==1) ? Wk : (mode==2) ? Wv : Wq;
  const float* bias = (mode==1) ? bk : (mode==2) ? bv : bq;

  __shared__ u16 lA[2][4096];   // [128 rows][32 k] bf16, k-groups-of-8 swizzled
  __shared__ u16 lB[2][4096];

  const int tid  = threadIdx.x;
  const int row0 = blockIdx.y * 128;
  const int col0 = blockIdx.x * 128;

  const int srow = tid >> 2;                    // 0..63
  const int sgp  = tid & 3;
  const int sgl  = sgp ^ ((srow >> 1) & 3);
  const u16* ga0 = A + (row0 + srow)      * 1024 + sgl * 8;
  const u16* ga1 = A + (row0 + srow + 64) * 1024 + sgl * 8;
  const u16* gb0 = W + (col0 + srow)      * 1024 + sgl * 8;
  const u16* gb1 = W + (col0 + srow + 64) * 1024 + sgl * 8;

  const int l  = tid & 63, w = tid >> 6;
  const int wr = w >> 1,  wc = w & 1;
  const int lr = l & 15,  grp = l >> 4;
  const int sw = (lr >> 1) & 3;
  int aoff[4], boff[4];
#pragma unroll
  for (int m = 0; m < 4; ++m) aoff[m] = (wr*64 + m*16 + lr)*32 + ((grp ^ sw) * 8);
#pragma unroll
  for (int n = 0; n < 4; ++n) boff[n] = (wc*64 + n*16 + lr)*32 + ((grp ^ sw) * 8);

  floatx4 acc[4][4];
#pragma unroll
  for (int m = 0; m < 4; ++m)
#pragma unroll
    for (int n = 0; n < 4; ++n) acc[m][n] = (floatx4){0.f, 0.f, 0.f, 0.f};

#define STAGE(buf, kt_) do { \
    const int k0_ = (kt_) * 32; \
    gld16(ga0 + k0_, &lA[(buf)][tid*8]); \
    gld16(ga1 + k0_, &lA[(buf)][2048 + tid*8]); \
    gld16(gb0 + k0_, &lB[(buf)][tid*8]); \
    gld16(gb1 + k0_, &lB[(buf)][2048 + tid*8]); \
  } while (0)

  STAGE(0, 0);
  __syncthreads();
  for (int kt = 0; kt < 32; ++kt) {
    const int cur = kt & 1;
    if (kt < 31) STAGE(cur ^ 1, kt + 1);
    short8 af[4], bf[4];
#pragma unroll
    for (int m = 0; m < 4; ++m) af[m] = *(const short8*)&lA[cur][aoff[m]];
#pragma unroll
    for (int n = 0; n < 4; ++n) bf[n] = *(const short8*)&lB[cur][boff[n]];
#pragma unroll
    for (int m = 0; m < 4; ++m)
#pragma unroll
      for (int n = 0; n < 4; ++n)
        acc[m][n] = __builtin_amdgcn_mfma_f32_16x16x32_bf16(af[m], bf[n], acc[m][n], 0, 0, 0);
    __syncthreads();
  }
#undef STAGE

  if (mode == 3) {
#pragma unroll
    for (int n = 0; n < 4; ++n) {
      const int cg = col0 + wc*64 + n*16 + lr;
      const float bb = bias[cg];
#pragma unroll
      for (int m = 0; m < 4; ++m) {
        const int rg = row0 + wr*64 + m*16 + grp*4;
#pragma unroll
        for (int j = 0; j < 4; ++j)
          Fo[(rg + j) * 1024 + cg] = acc[m][n][j] + bb;
      }
    }
  } else {
    const float sc = (mode == 0) ? 0.18033688011112042f : 1.0f;  // 0.125*log2(e) for Q
    u16* dst = (mode == 0) ? Qo : (mode == 1) ? Ko : Vo;
#pragma unroll
    for (int n = 0; n < 4; ++n) {
      const int cg = col0 + wc*64 + n*16 + lr;
      const float bb = bias[cg];
      const int h = cg >> 6, d = cg & 63;
#pragma unroll
      for (int m = 0; m < 4; ++m) {
#pragma unroll
        for (int j = 0; j < 4; ++j) {
          const int rg = row0 + wr*64 + m*16 + grp*4 + j;
          const int b = rg >> 11, s5 = rg & 2047;
          const float val = (acc[m][n][j] + bb) * sc;
          int idx;
          if (mode == 2) idx = ((b*16 + h)*64 + d)*2048 + s5;
          else           idx = ((b*16 + h)*2048 + s5)*64 + d;
          dst[idx] = f2bf(val);
        }
      }
    }
  }
}

// ---------------- flash attention v5: staged LDS + counted vmcnt + merged softmax --
// grid: 32x32 = 1024 blocks. 256 thr = 4 waves x 16 q-rows. KVBLK=64.
// S^T = mfma(K, Q): row=key, col=query(=lane&15). Softmax state per-lane scalar.
__global__ __launch_bounds__(256, 4) void k_attn(
    const u16* __restrict__ Q, const u16* __restrict__ K,
    const u16* __restrict__ V, u16* __restrict__ O)
{
  __shared__ u16 lK[2][4096];     // [64 keys][64 dk] groups-of-8 swizzled
  __shared__ u16 lV[2][4096];     // [64 dk][64 keys] (V^T) swizzled
  __shared__ u16 lP[4][1024];     // [wave][16 q][64 keys] group-swizzled (wave-private)

  const int tid = threadIdx.x;
  // XCD-chunked bijective swizzle: 1024 blocks, 128 per XCD -> 4 bh per XCD (L2-resident K/V)
  const int bid = (int)blockIdx.x + 32 * (int)blockIdx.y;
  const int lid = (bid & 7) * 128 + (bid >> 3);
  const int qt = 31 - (lid & 31);          // longest blocks first within chunk
  const int bh = lid >> 5;

  const int l = tid & 63, w = tid >> 6;
  const int lr = l & 15, grp = l >> 4;
  const int q0 = qt * 64;
  const int qw0 = q0 + w * 16;

  const u16* Qh = Q + (size_t)bh * 2048 * 64;
  const u16* Kh = K + (size_t)bh * 2048 * 64;
  const u16* Vh = V + (size_t)bh * 64 * 2048;

  // Q fragments (B-operand: lane holds Q[qw0+lr][kk*32+grp*8..+7])
  short8 qf[2];
#pragma unroll
  for (int kk = 0; kk < 2; ++kk)
    qf[kk] = *(const short8*)(Qh + (qw0 + lr)*64 + kk*32 + grp*8);

  floatx4 accO[4];                 // O^T: [d=dn*16+grp*4+j][q=lr]
  float mrow = -1e30f, lrow = 0.f;
#pragma unroll
  for (int dn = 0; dn < 4; ++dn) accO[dn] = (floatx4){0.f, 0.f, 0.f, 0.f};

  const int srow = tid >> 3, sgp = tid & 7;
  const int sgl = sgp ^ (srow & 7);
  const int nkt = qt + 1;
  u16* lPw = &lP[w][0];
  const int swz = lr & 7;

// 4 vmem instructions per wave per STAGEKV
#define STAGEKV(buf, kt_) do { \
    gld16(Kh + ((kt_)*64 + srow     )*64 + sgl*8, &lK[(buf)][tid*8]); \
    gld16(Kh + ((kt_)*64 + srow + 32)*64 + sgl*8, &lK[(buf)][2048 + tid*8]); \
    gld16(Vh + (srow     )*2048 + (kt_)*64 + sgl*8, &lV[(buf)][tid*8]); \
    gld16(Vh + (srow + 32)*2048 + (kt_)*64 + sgl*8, &lV[(buf)][2048 + tid*8]); \
  } while (0)

  STAGEKV(0, 0);

  for (int kt = 0; kt < nkt; ++kt) {
    const int cur = kt & 1;
    const bool more = (kt + 1 < nkt);
    if (more) STAGEKV(cur ^ 1, kt + 1);      // next tile's 4 loads stay in flight

    // counted wait: my previous-tile loads done; next tile's 4 may remain outstanding
    if (more) asm volatile("s_waitcnt vmcnt(4)" ::: "memory");
    else      asm volatile("s_waitcnt vmcnt(0)" ::: "memory");
    __builtin_amdgcn_sched_barrier(0);
    __builtin_amdgcn_s_barrier();            // all waves' tile-kt loads landed

    const int kb = kt * 64;
    if (kb <= qw0 + 15) {          // wave has at least one unmasked (q,key) pair
      // S^T = K Q^T : st[n] reg j -> key = kb+n*16+grp*4+j, query = qw0+lr
      floatx4 st[4];
#pragma unroll
      for (int n = 0; n < 4; ++n) st[n] = (floatx4){0.f, 0.f, 0.f, 0.f};
      __builtin_amdgcn_s_setprio(1);
#pragma unroll
      for (int n = 0; n < 4; ++n) {
        const int key = n*16 + lr;
#pragma unroll
        for (int kk = 0; kk < 2; ++kk) {
          const int gp = (kk*4 + grp) ^ (key & 7);
          short8 kf = *(const short8*)&lK[cur][key*64 + gp*8];
          st[n] = __builtin_amdgcn_mfma_f32_16x16x32_bf16(kf, qf[kk], st[n], 0, 0, 0);
        }
      }
      __builtin_amdgcn_s_setprio(0);

      // causal mask (only diagonal tile is partial)
      const int lim = qw0 + lr - kb;     // key offset <= lim is valid
      if (63 > lim) {
#pragma unroll
        for (int n = 0; n < 4; ++n)
#pragma unroll
          for (int j = 0; j < 4; ++j)
            if (n*16 + grp*4 + j > lim) st[n][j] = -1e30f;
      }

      // merged online softmax: local max+exp+sum first, then 2 butterfly (m,s) merges
      float mt0 = st[0][0];
#pragma unroll
      for (int n = 0; n < 4; ++n)
#pragma unroll
        for (int j = 0; j < 4; ++j) mt0 = fmaxf(mt0, st[n][j]);
      float ps = 0.f;
#pragma unroll
      for (int n = 0; n < 4; ++n)
#pragma unroll
        for (int j = 0; j < 4; ++j) {
          const float p = exp2f(st[n][j] - mt0);
          st[n][j] = p;
          ps += p;
        }
      float mA = mt0;
      {
        const float mo = __shfl_xor(mA, 16);
        const float so = __shfl_xor(ps, 16);
        const float mx = fmaxf(mA, mo);
        ps = ps * exp2f(mA - mx) + so * exp2f(mo - mx);
        mA = mx;
      }
      {
        const float mo = __shfl_xor(mA, 32);
        const float so = __shfl_xor(ps, 32);
        const float mx = fmaxf(mA, mo);
        ps = ps * exp2f(mA - mx) + so * exp2f(mo - mx);
        mA = mx;
      }
      const float mn = fmaxf(mrow, mA);
      const float alpha = exp2f(mrow - mn);
      lrow = lrow * alpha + ps * exp2f(mA - mn);
      const float fac = exp2f(mt0 - mn);     // this lane's local-P correction
      mrow = mn;
#pragma unroll
      for (int dn = 0; dn < 4; ++dn) accO[dn] *= alpha;

      // pack P*fac -> wave-private LDS [q][key], swizzled groups-of-8
#pragma unroll
      for (int n = 0; n < 4; ++n)
#pragma unroll
        for (int p2 = 0; p2 < 2; ++p2) {
          const unsigned pk = cvt_pk_bf16(st[n][2*p2] * fac, st[n][2*p2+1] * fac);
          const int pg = (2*n + (grp >> 1)) ^ swz;
          ((unsigned*)lPw)[lr*32 + pg*4 + (grp & 1)*2 + p2] = pk;
        }

      asm volatile("s_waitcnt lgkmcnt(0)" ::: "memory");

      short8 pa[2];
#pragma unroll
      for (int kk = 0; kk < 2; ++kk)
        pa[kk] = *(const short8*)&lPw[lr*64 + (((kk*4 + grp) ^ swz) * 8)];

      // O^T += V^T P : accO[dn] reg j -> d = dn*16+grp*4+j, q = qw0+lr
      __builtin_amdgcn_s_setprio(1);
#pragma unroll
      for (int dn = 0; dn < 4; ++dn) {
        const int d = dn*16 + lr;
#pragma unroll
        for (int kk = 0; kk < 2; ++kk) {
          const int gp = (kk*4 + grp) ^ (d & 7);
          short8 vf = *(const short8*)&lV[cur][d*64 + gp*8];
          accO[dn] = __builtin_amdgcn_mfma_f32_16x16x32_bf16(vf, pa[kk], accO[dn], 0, 0, 0);
        }
      }
      __builtin_amdgcn_s_setprio(0);
    }

    // all waves done reading buf[cur] before next iteration overwrites it
    asm volatile("s_waitcnt lgkmcnt(0)" ::: "memory");
    __builtin_amdgcn_sched_barrier(0);
    __builtin_amdgcn_s_barrier();
  }
#undef STAGEKV

  // epilogue: O[token][h*64+d] bf16, packed u32 stores
  const int b = bh >> 4, h = bh & 15;
  const float inv = 1.0f / lrow;
  const int token = b*2048 + qw0 + lr;
#pragma unroll
  for (int dn = 0; dn < 4; ++dn)
#pragma unroll
    for (int p2 = 0; p2 < 2; ++p2) {
      const unsigned pk = cvt_pk_bf16(accO[dn][2*p2] * inv, accO[dn][2*p2+1] * inv);
      *(unsigned*)&O[token*1024 + h*64 + dn*16 + grp*4 + 2*p2] = pk;
    }
}

// ---------------- launcher ----------------
extern "C" void kernel_launch(void* const* d_in, const int* in_sizes, int n_in,
                              void* d_out, int out_size, void* d_ws, size_t ws_size,
                              hipStream_t stream) {
  const float* x  = (const float*)d_in[0];
  const float* Wq = (const float*)d_in[1];
  const float* bq = (const float*)d_in[2];
  const float* Wk = (const float*)d_in[3];
  const float* bk = (const float*)d_in[4];
  const float* Wv = (const float*)d_in[5];
  const float* bv = (const float*)d_in[6];
  const float* Wo = (const float*)d_in[7];
  const float* bo = (const float*)d_in[8];
  float* out = (float*)d_out;

  char* ws = (char*)d_ws;
  u16* xb  = (u16*)(ws + 0);          // [4096][1024] bf16
  u16* wqb = (u16*)(ws + 8388608);
  u16* wkb = (u16*)(ws + 10485760);
  u16* wvb = (u16*)(ws + 12582912);
  u16* wob = (u16*)(ws + 14680064);
  u16* Qb  = (u16*)(ws + 16777216);   // [32][2048][64]
  u16* Kb  = (u16*)(ws + 25165824);   // [32][2048][64]
  u16* Vb  = (u16*)(ws + 33554432);   // [32][64][2048]
  u16* Ab  = (u16*)(ws + 41943040);   // [4096][1024]

  k_cvt_all<<<dim3(8192), 256, 0, stream>>>(x, Wq, Wk, Wv, Wo, xb, wqb, wkb, wvb, wob);

  k_gemm<<<dim3(8, 32, 3), 256, 0, stream>>>(xb, wqb, wkb, wvb, bq, bk, bv,
                                             Qb, Kb, Vb, nullptr, 0);

  k_attn<<<dim3(32, 32), 256, 0, stream>>>(Qb, Kb, Vb, Ab);

  k_gemm<<<dim3(8, 32, 1), 256, 0, stream>>>(Ab, wob, wob, wob, bo, bo, bo,
                                             nullptr, nullptr, nullptr, out, 1);
}

// Round 6
// 146.298 us; speedup vs baseline: 1.4714x; 1.2504x over previous
//
#include <hip/hip_runtime.h>

typedef unsigned short u16;
typedef __attribute__((ext_vector_type(8))) short short8;
typedef __attribute__((ext_vector_type(4))) float floatx4;

__device__ __forceinline__ u16 f2bf(float x){
  union { float f; unsigned u; } v; v.f = x;
  unsigned r = v.u + 0x7fffu + ((v.u >> 16) & 1u);
  return (u16)(r >> 16);
}

__device__ __forceinline__ unsigned cvt_pk_bf16(float lo, float hi){
  unsigned r;
  asm("v_cvt_pk_bf16_f32 %0, %1, %2" : "=v"(r) : "v"(lo), "v"(hi));
  return r;
}

__device__ __forceinline__ void gld16(const u16* g, u16* l){
  __builtin_amdgcn_global_load_lds(
      (const __attribute__((address_space(1))) void*)g,
      (__attribute__((address_space(3))) void*)l, 16, 0, 0);
}

// ---------------- fused fp32 -> bf16 convert (x + 4 weights, one launch) -------
__global__ void k_cvt_all(const float* __restrict__ x,
                          const float* __restrict__ wq, const float* __restrict__ wk,
                          const float* __restrict__ wv, const float* __restrict__ wo,
                          u16* __restrict__ xb, u16* __restrict__ wqb, u16* __restrict__ wkb,
                          u16* __restrict__ wvb, u16* __restrict__ wob){
  const int i = blockIdx.x * 256 + threadIdx.x;   // float4 index, total 2097152
  const float* s; u16* d; int off;
  if (i < 1048576) { s = x; d = xb; off = i; }
  else {
    const int j = i - 1048576;
    const int wsel = j >> 18;          // 262144 f4 per weight
    off = j & 262143;
    s = (wsel==0) ? wq : (wsel==1) ? wk : (wsel==2) ? wv : wo;
    d = (wsel==0) ? wqb : (wsel==1) ? wkb : (wsel==2) ? wvb : wob;
  }
  const float4 f = ((const float4*)s)[off];
  unsigned lo = (unsigned)f2bf(f.x) | ((unsigned)f2bf(f.y) << 16);
  unsigned hi = (unsigned)f2bf(f.z) | ((unsigned)f2bf(f.w) << 16);
  ((uint2*)d)[off] = make_uint2(lo, hi);
}

// ---------------- GEMM: C[4096][1024] = A[4096][1024] * W[1024][1024]^T + b --------
// mode 0: Q (bf16 out, [bh][s][64], *qscale)   mode 1: K (bf16, [bh][s][64])
// mode 2: V (bf16, [bh][64][s])                mode 3: fp32 out [4096][1024]
__global__ __launch_bounds__(256) void k_gemm(
    const u16* __restrict__ A,
    const u16* __restrict__ Wq, const u16* __restrict__ Wk, const u16* __restrict__ Wv,
    const float* __restrict__ bq, const float* __restrict__ bk, const float* __restrict__ bv,
    u16* __restrict__ Qo, u16* __restrict__ Ko, u16* __restrict__ Vo,
    float* __restrict__ Fo, int oproj)
{
  const int mode = oproj ? 3 : (int)blockIdx.z;
  const u16* W      = (mode==1) ? Wk : (mode==2) ? Wv : Wq;
  const float* bias = (mode==1) ? bk : (mode==2) ? bv : bq;

  __shared__ u16 lA[2][4096];   // [128 rows][32 k] bf16, k-groups-of-8 swizzled
  __shared__ u16 lB[2][4096];

  const int tid  = threadIdx.x;
  const int row0 = blockIdx.y * 128;
  const int col0 = blockIdx.x * 128;

  const int srow = tid >> 2;                    // 0..63
  const int sgp  = tid & 3;
  const int sgl  = sgp ^ ((srow >> 1) & 3);
  const u16* ga0 = A + (row0 + srow)      * 1024 + sgl * 8;
  const u16* ga1 = A + (row0 + srow + 64) * 1024 + sgl * 8;
  const u16* gb0 = W + (col0 + srow)      * 1024 + sgl * 8;
  const u16* gb1 = W + (col0 + srow + 64) * 1024 + sgl * 8;

  const int l  = tid & 63, w = tid >> 6;
  const int wr = w >> 1,  wc = w & 1;
  const int lr = l & 15,  grp = l >> 4;
  const int sw = (lr >> 1) & 3;
  int aoff[4], boff[4];
#pragma unroll
  for (int m = 0; m < 4; ++m) aoff[m] = (wr*64 + m*16 + lr)*32 + ((grp ^ sw) * 8);
#pragma unroll
  for (int n = 0; n < 4; ++n) boff[n] = (wc*64 + n*16 + lr)*32 + ((grp ^ sw) * 8);

  floatx4 acc[4][4];
#pragma unroll
  for (int m = 0; m < 4; ++m)
#pragma unroll
    for (int n = 0; n < 4; ++n) acc[m][n] = (floatx4){0.f, 0.f, 0.f, 0.f};

#define STAGE(buf, kt_) do { \
    const int k0_ = (kt_) * 32; \
    gld16(ga0 + k0_, &lA[(buf)][tid*8]); \
    gld16(ga1 + k0_, &lA[(buf)][2048 + tid*8]); \
    gld16(gb0 + k0_, &lB[(buf)][tid*8]); \
    gld16(gb1 + k0_, &lB[(buf)][2048 + tid*8]); \
  } while (0)

  STAGE(0, 0);
  __syncthreads();
  for (int kt = 0; kt < 32; ++kt) {
    const int cur = kt & 1;
    if (kt < 31) STAGE(cur ^ 1, kt + 1);
    short8 af[4], bf[4];
#pragma unroll
    for (int m = 0; m < 4; ++m) af[m] = *(const short8*)&lA[cur][aoff[m]];
#pragma unroll
    for (int n = 0; n < 4; ++n) bf[n] = *(const short8*)&lB[cur][boff[n]];
#pragma unroll
    for (int m = 0; m < 4; ++m)
#pragma unroll
      for (int n = 0; n < 4; ++n)
        acc[m][n] = __builtin_amdgcn_mfma_f32_16x16x32_bf16(af[m], bf[n], acc[m][n], 0, 0, 0);
    __syncthreads();
  }
#undef STAGE

  if (mode == 3) {
#pragma unroll
    for (int n = 0; n < 4; ++n) {
      const int cg = col0 + wc*64 + n*16 + lr;
      const float bb = bias[cg];
#pragma unroll
      for (int m = 0; m < 4; ++m) {
        const int rg = row0 + wr*64 + m*16 + grp*4;
#pragma unroll
        for (int j = 0; j < 4; ++j)
          Fo[(rg + j) * 1024 + cg] = acc[m][n][j] + bb;
      }
    }
  } else {
    const float sc = (mode == 0) ? 0.18033688011112042f : 1.0f;  // 0.125*log2(e) for Q
    u16* dst = (mode == 0) ? Qo : (mode == 1) ? Ko : Vo;
#pragma unroll
    for (int n = 0; n < 4; ++n) {
      const int cg = col0 + wc*64 + n*16 + lr;
      const float bb = bias[cg];
      const int h = cg >> 6, d = cg & 63;
#pragma unroll
      for (int m = 0; m < 4; ++m) {
#pragma unroll
        for (int j = 0; j < 4; ++j) {
          const int rg = row0 + wr*64 + m*16 + grp*4 + j;
          const int b = rg >> 11, s5 = rg & 2047;
          const float val = (acc[m][n][j] + bb) * sc;
          int idx;
          if (mode == 2) idx = ((b*16 + h)*64 + d)*2048 + s5;
          else           idx = ((b*16 + h)*2048 + s5)*64 + d;
          dst[idx] = f2bf(val);
        }
      }
    }
  }
}

// ---------------- flash attention v6: balanced tile-pairs ----------
// grid: 512 blocks x 256 thr (4 waves x 16 q-rows). KVBLK=64, QBLK=64.
// Block bid -> (bh, pr); processes q-tiles (31-pr) then (pr) sequentially:
// exactly 33 K-tile phases per block regardless of bid -> perfect balance.
// S^T = mfma(K, Q): row=key, col=query(=lane&15). Softmax per-lane scalar.
__global__ __launch_bounds__(256, 4) void k_attn(
    const u16* __restrict__ Q, const u16* __restrict__ K,
    const u16* __restrict__ V, u16* __restrict__ O)
{
  __shared__ u16 lK[2][4096];     // [64 keys][64 dk] groups-of-8 swizzled
  __shared__ u16 lV[2][4096];     // [64 dk][64 keys] (V^T) swizzled
  __shared__ u16 lP[4][1024];     // [wave][16 q][64 keys] group-swizzled (wave-private)

  const int tid = threadIdx.x;
  const int bid = (int)blockIdx.x;
  const int xcd = bid & 7, r = bid >> 3;       // 64 blocks per XCD
  const int bh = xcd * 4 + (r >> 4);           // 4 bh per XCD -> K/V L2-resident
  const int pr = r & 15;                       // pair index: tiles (31-pr, pr)

  const int l = tid & 63, w = tid >> 6;
  const int lr = l & 15, grp = l >> 4;

  const u16* Qh = Q + (size_t)bh * 2048 * 64;
  const u16* Kh = K + (size_t)bh * 2048 * 64;
  const u16* Vh = V + (size_t)bh * 64 * 2048;

  const int srow = tid >> 3, sgp = tid & 7;
  const int sgl = sgp ^ (srow & 7);
  u16* lPw = &lP[w][0];
  const int swz = lr & 7;
  const int b = bh >> 4, h = bh & 15;

// 4 vmem instructions per wave per STAGEKV
#define STAGEKV(buf, kt_) do { \
    gld16(Kh + ((kt_)*64 + srow     )*64 + sgl*8, &lK[(buf)][tid*8]); \
    gld16(Kh + ((kt_)*64 + srow + 32)*64 + sgl*8, &lK[(buf)][2048 + tid*8]); \
    gld16(Vh + (srow     )*2048 + (kt_)*64 + sgl*8, &lV[(buf)][tid*8]); \
    gld16(Vh + (srow + 32)*2048 + (kt_)*64 + sgl*8, &lV[(buf)][2048 + tid*8]); \
  } while (0)

#pragma unroll
  for (int pass = 0; pass < 2; ++pass) {
    const int qt = pass ? pr : (31 - pr);
    const int qw0 = qt * 64 + w * 16;
    const int nkt = qt + 1;

    // Q fragments (B-operand: lane holds Q[qw0+lr][kk*32+grp*8..+7])
    short8 qf[2];
#pragma unroll
    for (int kk = 0; kk < 2; ++kk)
      qf[kk] = *(const short8*)(Qh + (qw0 + lr)*64 + kk*32 + grp*8);

    floatx4 accO[4];               // O^T: [d=dn*16+grp*4+j][q=lr]
    float mrow = -1e30f, lrow = 0.f;
#pragma unroll
    for (int dn = 0; dn < 4; ++dn) accO[dn] = (floatx4){0.f, 0.f, 0.f, 0.f};

    STAGEKV(0, 0);
    __syncthreads();

    for (int kt = 0; kt < nkt; ++kt) {
      const int cur = kt & 1;
      if (kt + 1 < nkt) STAGEKV(cur ^ 1, kt + 1);
      const int kb = kt * 64;

      // S^T = K Q^T : st[n] reg j -> key = kb+n*16+grp*4+j, query = qw0+lr
      floatx4 st[4];
#pragma unroll
      for (int n = 0; n < 4; ++n) st[n] = (floatx4){0.f, 0.f, 0.f, 0.f};
#pragma unroll
      for (int n = 0; n < 4; ++n) {
        const int key = n*16 + lr;
#pragma unroll
        for (int kk = 0; kk < 2; ++kk) {
          const int gp = (kk*4 + grp) ^ (key & 7);
          short8 kf = *(const short8*)&lK[cur][key*64 + gp*8];
          st[n] = __builtin_amdgcn_mfma_f32_16x16x32_bf16(kf, qf[kk], st[n], 0, 0, 0);
        }
      }

      // causal mask (only diagonal tile kt==qt is partial)
      const int lim = qw0 + lr - kb;     // key offset <= lim is valid
      if (63 > lim) {
#pragma unroll
        for (int n = 0; n < 4; ++n)
#pragma unroll
          for (int j = 0; j < 4; ++j)
            if (n*16 + grp*4 + j > lim) st[n][j] = -1e30f;
      }

      // online softmax: per-lane scalar state, 2 shuffles per reduce
      float mt = st[0][0];
#pragma unroll
      for (int n = 0; n < 4; ++n)
#pragma unroll
        for (int j = 0; j < 4; ++j) mt = fmaxf(mt, st[n][j]);
      mt = fmaxf(mt, __shfl_xor(mt, 16));
      mt = fmaxf(mt, __shfl_xor(mt, 32));
      const float mn = fmaxf(mrow, mt);
      const float alpha = exp2f(mrow - mn);
      mrow = mn;
      float ps = 0.f;
#pragma unroll
      for (int n = 0; n < 4; ++n)
#pragma unroll
        for (int j = 0; j < 4; ++j) {
          const float p = exp2f(st[n][j] - mn);
          st[n][j] = p;
          ps += p;
        }
      ps += __shfl_xor(ps, 16);
      ps += __shfl_xor(ps, 32);
      lrow = lrow * alpha + ps;
#pragma unroll
      for (int dn = 0; dn < 4; ++dn) accO[dn] *= alpha;

      // pack P -> wave-private LDS [q][key], swizzled groups-of-8
#pragma unroll
      for (int n = 0; n < 4; ++n)
#pragma unroll
        for (int p2 = 0; p2 < 2; ++p2) {
          const unsigned pk = cvt_pk_bf16(st[n][2*p2], st[n][2*p2+1]);
          const int pg = (2*n + (grp >> 1)) ^ swz;
          ((unsigned*)lPw)[lr*32 + pg*4 + (grp & 1)*2 + p2] = pk;
        }

      asm volatile("s_waitcnt lgkmcnt(0)" ::: "memory");

      short8 pa[2];
#pragma unroll
      for (int kk = 0; kk < 2; ++kk)
        pa[kk] = *(const short8*)&lPw[lr*64 + (((kk*4 + grp) ^ swz) * 8)];

      // O^T += V^T P : accO[dn] reg j -> d = dn*16+grp*4+j, q = qw0+lr
#pragma unroll
      for (int dn = 0; dn < 4; ++dn) {
        const int d = dn*16 + lr;
#pragma unroll
        for (int kk = 0; kk < 2; ++kk) {
          const int gp = (kk*4 + grp) ^ (d & 7);
          short8 vf = *(const short8*)&lV[cur][d*64 + gp*8];
          accO[dn] = __builtin_amdgcn_mfma_f32_16x16x32_bf16(vf, pa[kk], accO[dn], 0, 0, 0);
        }
      }
      __syncthreads();
    }

    // epilogue: O[token][h*64+d] bf16, packed u32 stores
    const float inv = 1.0f / lrow;
    const int token = b*2048 + qw0 + lr;
#pragma unroll
    for (int dn = 0; dn < 4; ++dn)
#pragma unroll
      for (int p2 = 0; p2 < 2; ++p2) {
        const unsigned pk = cvt_pk_bf16(accO[dn][2*p2] * inv, accO[dn][2*p2+1] * inv);
        *(unsigned*)&O[token*1024 + h*64 + dn*16 + grp*4 + 2*p2] = pk;
      }
  }
#undef STAGEKV
}

// ---------------- launcher ----------------
extern "C" void kernel_launch(void* const* d_in, const int* in_sizes, int n_in,
                              void* d_out, int out_size, void* d_ws, size_t ws_size,
                              hipStream_t stream) {
  const float* x  = (const float*)d_in[0];
  const float* Wq = (const float*)d_in[1];
  const float* bq = (const float*)d_in[2];
  const float* Wk = (const float*)d_in[3];
  const float* bk = (const float*)d_in[4];
  const float* Wv = (const float*)d_in[5];
  const float* bv = (const float*)d_in[6];
  const float* Wo = (const float*)d_in[7];
  const float* bo = (const float*)d_in[8];
  float* out = (float*)d_out;

  char* ws = (char*)d_ws;
  u16* xb  = (u16*)(ws + 0);          // [4096][1024] bf16
  u16* wqb = (u16*)(ws + 8388608);
  u16* wkb = (u16*)(ws + 10485760);
  u16* wvb = (u16*)(ws + 12582912);
  u16* wob = (u16*)(ws + 14680064);
  u16* Qb  = (u16*)(ws + 16777216);   // [32][2048][64]
  u16* Kb  = (u16*)(ws + 25165824);   // [32][2048][64]
  u16* Vb  = (u16*)(ws + 33554432);   // [32][64][2048]
  u16* Ab  = (u16*)(ws + 41943040);   // [4096][1024]

  k_cvt_all<<<dim3(8192), 256, 0, stream>>>(x, Wq, Wk, Wv, Wo, xb, wqb, wkb, wvb, wob);

  k_gemm<<<dim3(8, 32, 3), 256, 0, stream>>>(xb, wqb, wkb, wvb, bq, bk, bv,
                                             Qb, Kb, Vb, nullptr, 0);

  k_attn<<<dim3(512), 256, 0, stream>>>(Qb, Kb, Vb, Ab);

  k_gemm<<<dim3(8, 32, 1), 256, 0, stream>>>(Ab, wob, wob, wob, bo, bo, bo,
                                             nullptr, nullptr, nullptr, out, 1);
}

// Round 7
// 125.951 us; speedup vs baseline: 1.7091x; 1.1616x over previous
//
#include <hip/hip_runtime.h>

typedef unsigned short u16;
typedef __attribute__((ext_vector_type(8))) short short8;
typedef __attribute__((ext_vector_type(4))) float floatx4;

__device__ __forceinline__ u16 f2bf(float x){
  union { float f; unsigned u; } v; v.f = x;
  unsigned r = v.u + 0x7fffu + ((v.u >> 16) & 1u);
  return (u16)(r >> 16);
}

__device__ __forceinline__ unsigned cvt_pk_bf16(float lo, float hi){
  unsigned r;
  asm("v_cvt_pk_bf16_f32 %0, %1, %2" : "=v"(r) : "v"(lo), "v"(hi));
  return r;
}

__device__ __forceinline__ void gld16(const u16* g, u16* l){
  __builtin_amdgcn_global_load_lds(
      (const __attribute__((address_space(1))) void*)g,
      (__attribute__((address_space(3))) void*)l, 16, 0, 0);
}

// ---------------- fused fp32 -> bf16 convert (x + 4 weights, one launch) -------
__global__ void k_cvt_all(const float* __restrict__ x,
                          const float* __restrict__ wq, const float* __restrict__ wk,
                          const float* __restrict__ wv, const float* __restrict__ wo,
                          u16* __restrict__ xb, u16* __restrict__ wqb, u16* __restrict__ wkb,
                          u16* __restrict__ wvb, u16* __restrict__ wob){
  const int i = blockIdx.x * 256 + threadIdx.x;   // float4 index, total 2097152
  const float* s; u16* d; int off;
  if (i < 1048576) { s = x; d = xb; off = i; }
  else {
    const int j = i - 1048576;
    const int wsel = j >> 18;          // 262144 f4 per weight
    off = j & 262143;
    s = (wsel==0) ? wq : (wsel==1) ? wk : (wsel==2) ? wv : wo;
    d = (wsel==0) ? wqb : (wsel==1) ? wkb : (wsel==2) ? wvb : wob;
  }
  const float4 f = ((const float4*)s)[off];
  unsigned lo = (unsigned)f2bf(f.x) | ((unsigned)f2bf(f.y) << 16);
  unsigned hi = (unsigned)f2bf(f.z) | ((unsigned)f2bf(f.w) << 16);
  ((uint2*)d)[off] = make_uint2(lo, hi);
}

// ---------------- QKV GEMM: 128x128 tile, XCD-chunked placement ----------------
// 768 blocks; XCD chunk = {8 y-panels x 4 x-panels x 3 modes} -> A 2MB + W 3MB ~ L2.
// mode 0: Q (bf16, [bh][s][64], *qscale)  mode 1: K (bf16)  mode 2: V (bf16, [bh][64][s])
__global__ __launch_bounds__(256) void k_gemm_qkv(
    const u16* __restrict__ A,
    const u16* __restrict__ Wq, const u16* __restrict__ Wk, const u16* __restrict__ Wv,
    const float* __restrict__ bq, const float* __restrict__ bk, const float* __restrict__ bv,
    u16* __restrict__ Qo, u16* __restrict__ Ko, u16* __restrict__ Vo)
{
  // XCD-chunked decode: bid%8 = XCD; chunk covers y0..y0+7 (A rows), x0..x0+3, all z
  const int bid = (int)blockIdx.x;
  const int xcd = bid & 7;
  const int i5  = bid >> 3;                    // 0..95
  const int xb_ = ((xcd >> 2) << 2) + (i5 & 3);        // 0..7
  const int rest = i5 >> 2;                    // 0..23
  const int yb_ = ((xcd & 3) << 3) + (rest & 7);       // 0..31
  const int mode = rest >> 3;                  // 0..2

  const u16* W      = (mode==1) ? Wk : (mode==2) ? Wv : Wq;
  const float* bias = (mode==1) ? bk : (mode==2) ? bv : bq;

  __shared__ u16 lA[2][4096];   // [128 rows][32 k] bf16, k-groups-of-8 swizzled
  __shared__ u16 lB[2][4096];

  const int tid  = threadIdx.x;
  const int row0 = yb_ * 128;
  const int col0 = xb_ * 128;

  const int srow = tid >> 2;                    // 0..63
  const int sgp  = tid & 3;
  const int sgl  = sgp ^ ((srow >> 1) & 3);
  const u16* ga0 = A + (row0 + srow)      * 1024 + sgl * 8;
  const u16* ga1 = A + (row0 + srow + 64) * 1024 + sgl * 8;
  const u16* gb0 = W + (col0 + srow)      * 1024 + sgl * 8;
  const u16* gb1 = W + (col0 + srow + 64) * 1024 + sgl * 8;

  const int l  = tid & 63, w = tid >> 6;
  const int wr = w >> 1,  wc = w & 1;
  const int lr = l & 15,  grp = l >> 4;
  const int sw = (lr >> 1) & 3;
  int aoff[4], boff[4];
#pragma unroll
  for (int m = 0; m < 4; ++m) aoff[m] = (wr*64 + m*16 + lr)*32 + ((grp ^ sw) * 8);
#pragma unroll
  for (int n = 0; n < 4; ++n) boff[n] = (wc*64 + n*16 + lr)*32 + ((grp ^ sw) * 8);

  floatx4 acc[4][4];
#pragma unroll
  for (int m = 0; m < 4; ++m)
#pragma unroll
    for (int n = 0; n < 4; ++n) acc[m][n] = (floatx4){0.f, 0.f, 0.f, 0.f};

#define STAGE(buf, kt_) do { \
    const int k0_ = (kt_) * 32; \
    gld16(ga0 + k0_, &lA[(buf)][tid*8]); \
    gld16(ga1 + k0_, &lA[(buf)][2048 + tid*8]); \
    gld16(gb0 + k0_, &lB[(buf)][tid*8]); \
    gld16(gb1 + k0_, &lB[(buf)][2048 + tid*8]); \
  } while (0)

  STAGE(0, 0);
  __syncthreads();
  for (int kt = 0; kt < 32; ++kt) {
    const int cur = kt & 1;
    if (kt < 31) STAGE(cur ^ 1, kt + 1);
    short8 af[4], bf[4];
#pragma unroll
    for (int m = 0; m < 4; ++m) af[m] = *(const short8*)&lA[cur][aoff[m]];
#pragma unroll
    for (int n = 0; n < 4; ++n) bf[n] = *(const short8*)&lB[cur][boff[n]];
#pragma unroll
    for (int m = 0; m < 4; ++m)
#pragma unroll
      for (int n = 0; n < 4; ++n)
        acc[m][n] = __builtin_amdgcn_mfma_f32_16x16x32_bf16(af[m], bf[n], acc[m][n], 0, 0, 0);
    __syncthreads();
  }
#undef STAGE

  const float sc = (mode == 0) ? 0.18033688011112042f : 1.0f;  // 0.125*log2(e) for Q
  u16* dst = (mode == 0) ? Qo : (mode == 1) ? Ko : Vo;
#pragma unroll
  for (int n = 0; n < 4; ++n) {
    const int cg = col0 + wc*64 + n*16 + lr;
    const float bb = bias[cg];
    const int h = cg >> 6, d = cg & 63;
#pragma unroll
    for (int m = 0; m < 4; ++m) {
#pragma unroll
      for (int j = 0; j < 4; ++j) {
        const int rg = row0 + wr*64 + m*16 + grp*4 + j;
        const int b = rg >> 11, s5 = rg & 2047;
        const float val = (acc[m][n][j] + bb) * sc;
        int idx;
        if (mode == 2) idx = ((b*16 + h)*64 + d)*2048 + s5;
        else           idx = ((b*16 + h)*2048 + s5)*64 + d;
        dst[idx] = f2bf(val);
      }
    }
  }
}

// ---------------- O-proj GEMM: 64x128 tile, 512 blocks (2/CU), XCD-chunked ------
// C[4096][1024] fp32 = A[4096][1024]bf16 * Wo^T + bo
__global__ __launch_bounds__(256) void k_gemm_o(
    const u16* __restrict__ A, const u16* __restrict__ W,
    const float* __restrict__ bias, float* __restrict__ Fo)
{
  // XCD chunk = {16 y-panels(64 rows) x 4 x-panels} -> A 2MB + W 1MB, L2-fits
  const int bid = (int)blockIdx.x;
  const int xcd = bid & 7;
  const int i5  = bid >> 3;                    // 0..63
  const int xb_ = ((xcd >> 2) << 2) + (i5 & 3);        // 0..7
  const int yb_ = ((xcd & 3) << 4) + (i5 >> 2);        // 0..63

  __shared__ u16 lA[2][2048];   // [64 rows][32 k]
  __shared__ u16 lB[2][4096];   // [128 rows][32 k]

  const int tid  = threadIdx.x;
  const int row0 = yb_ * 64;
  const int col0 = xb_ * 128;

  const int srow = tid >> 2;                    // 0..63
  const int sgp  = tid & 3;
  const int sgl  = sgp ^ ((srow >> 1) & 3);
  const u16* ga0 = A + (row0 + srow)      * 1024 + sgl * 8;
  const u16* gb0 = W + (col0 + srow)      * 1024 + sgl * 8;
  const u16* gb1 = W + (col0 + srow + 64) * 1024 + sgl * 8;

  const int l  = tid & 63, w = tid >> 6;
  const int wr = w >> 1,  wc = w & 1;          // 2x2 wave grid: 32-row x 64-col
  const int lr = l & 15,  grp = l >> 4;
  const int sw = (lr >> 1) & 3;
  int aoff[2], boff[4];
#pragma unroll
  for (int m = 0; m < 2; ++m) aoff[m] = (wr*32 + m*16 + lr)*32 + ((grp ^ sw) * 8);
#pragma unroll
  for (int n = 0; n < 4; ++n) boff[n] = (wc*64 + n*16 + lr)*32 + ((grp ^ sw) * 8);

  floatx4 acc[2][4];
#pragma unroll
  for (int m = 0; m < 2; ++m)
#pragma unroll
    for (int n = 0; n < 4; ++n) acc[m][n] = (floatx4){0.f, 0.f, 0.f, 0.f};

#define STAGE(buf, kt_) do { \
    const int k0_ = (kt_) * 32; \
    gld16(ga0 + k0_, &lA[(buf)][tid*8]); \
    gld16(gb0 + k0_, &lB[(buf)][tid*8]); \
    gld16(gb1 + k0_, &lB[(buf)][2048 + tid*8]); \
  } while (0)

  STAGE(0, 0);
  __syncthreads();
  for (int kt = 0; kt < 32; ++kt) {
    const int cur = kt & 1;
    if (kt < 31) STAGE(cur ^ 1, kt + 1);
    short8 af[2], bf[4];
#pragma unroll
    for (int m = 0; m < 2; ++m) af[m] = *(const short8*)&lA[cur][aoff[m]];
#pragma unroll
    for (int n = 0; n < 4; ++n) bf[n] = *(const short8*)&lB[cur][boff[n]];
#pragma unroll
    for (int m = 0; m < 2; ++m)
#pragma unroll
      for (int n = 0; n < 4; ++n)
        acc[m][n] = __builtin_amdgcn_mfma_f32_16x16x32_bf16(af[m], bf[n], acc[m][n], 0, 0, 0);
    __syncthreads();
  }
#undef STAGE

#pragma unroll
  for (int n = 0; n < 4; ++n) {
    const int cg = col0 + wc*64 + n*16 + lr;
    const float bb = bias[cg];
#pragma unroll
    for (int m = 0; m < 2; ++m) {
      const int rg = row0 + wr*32 + m*16 + grp*4;
#pragma unroll
      for (int j = 0; j < 4; ++j)
        Fo[(rg + j) * 1024 + cg] = acc[m][n][j] + bb;
    }
  }
}

// ---------------- flash attention v6: balanced tile-pairs (unchanged) ----------
__global__ __launch_bounds__(256, 4) void k_attn(
    const u16* __restrict__ Q, const u16* __restrict__ K,
    const u16* __restrict__ V, u16* __restrict__ O)
{
  __shared__ u16 lK[2][4096];     // [64 keys][64 dk] groups-of-8 swizzled
  __shared__ u16 lV[2][4096];     // [64 dk][64 keys] (V^T) swizzled
  __shared__ u16 lP[4][1024];     // [wave][16 q][64 keys] group-swizzled (wave-private)

  const int tid = threadIdx.x;
  const int bid = (int)blockIdx.x;
  const int xcd = bid & 7, r = bid >> 3;       // 64 blocks per XCD
  const int bh = xcd * 4 + (r >> 4);           // 4 bh per XCD -> K/V L2-resident
  const int pr = r & 15;                       // pair index: tiles (31-pr, pr)

  const int l = tid & 63, w = tid >> 6;
  const int lr = l & 15, grp = l >> 4;

  const u16* Qh = Q + (size_t)bh * 2048 * 64;
  const u16* Kh = K + (size_t)bh * 2048 * 64;
  const u16* Vh = V + (size_t)bh * 64 * 2048;

  const int srow = tid >> 3, sgp = tid & 7;
  const int sgl = sgp ^ (srow & 7);
  u16* lPw = &lP[w][0];
  const int swz = lr & 7;
  const int b = bh >> 4, h = bh & 15;

#define STAGEKV(buf, kt_) do { \
    gld16(Kh + ((kt_)*64 + srow     )*64 + sgl*8, &lK[(buf)][tid*8]); \
    gld16(Kh + ((kt_)*64 + srow + 32)*64 + sgl*8, &lK[(buf)][2048 + tid*8]); \
    gld16(Vh + (srow     )*2048 + (kt_)*64 + sgl*8, &lV[(buf)][tid*8]); \
    gld16(Vh + (srow + 32)*2048 + (kt_)*64 + sgl*8, &lV[(buf)][2048 + tid*8]); \
  } while (0)

#pragma unroll
  for (int pass = 0; pass < 2; ++pass) {
    const int qt = pass ? pr : (31 - pr);
    const int qw0 = qt * 64 + w * 16;
    const int nkt = qt + 1;

    short8 qf[2];
#pragma unroll
    for (int kk = 0; kk < 2; ++kk)
      qf[kk] = *(const short8*)(Qh + (qw0 + lr)*64 + kk*32 + grp*8);

    floatx4 accO[4];               // O^T: [d=dn*16+grp*4+j][q=lr]
    float mrow = -1e30f, lrow = 0.f;
#pragma unroll
    for (int dn = 0; dn < 4; ++dn) accO[dn] = (floatx4){0.f, 0.f, 0.f, 0.f};

    STAGEKV(0, 0);
    __syncthreads();

    for (int kt = 0; kt < nkt; ++kt) {
      const int cur = kt & 1;
      if (kt + 1 < nkt) STAGEKV(cur ^ 1, kt + 1);
      const int kb = kt * 64;

      floatx4 st[4];
#pragma unroll
      for (int n = 0; n < 4; ++n) st[n] = (floatx4){0.f, 0.f, 0.f, 0.f};
#pragma unroll
      for (int n = 0; n < 4; ++n) {
        const int key = n*16 + lr;
#pragma unroll
        for (int kk = 0; kk < 2; ++kk) {
          const int gp = (kk*4 + grp) ^ (key & 7);
          short8 kf = *(const short8*)&lK[cur][key*64 + gp*8];
          st[n] = __builtin_amdgcn_mfma_f32_16x16x32_bf16(kf, qf[kk], st[n], 0, 0, 0);
        }
      }

      const int lim = qw0 + lr - kb;     // key offset <= lim is valid
      if (63 > lim) {
#pragma unroll
        for (int n = 0; n < 4; ++n)
#pragma unroll
          for (int j = 0; j < 4; ++j)
            if (n*16 + grp*4 + j > lim) st[n][j] = -1e30f;
      }

      float mt = st[0][0];
#pragma unroll
      for (int n = 0; n < 4; ++n)
#pragma unroll
        for (int j = 0; j < 4; ++j) mt = fmaxf(mt, st[n][j]);
      mt = fmaxf(mt, __shfl_xor(mt, 16));
      mt = fmaxf(mt, __shfl_xor(mt, 32));
      const float mn = fmaxf(mrow, mt);
      const float alpha = exp2f(mrow - mn);
      mrow = mn;
      float ps = 0.f;
#pragma unroll
      for (int n = 0; n < 4; ++n)
#pragma unroll
        for (int j = 0; j < 4; ++j) {
          const float p = exp2f(st[n][j] - mn);
          st[n][j] = p;
          ps += p;
        }
      ps += __shfl_xor(ps, 16);
      ps += __shfl_xor(ps, 32);
      lrow = lrow * alpha + ps;
#pragma unroll
      for (int dn = 0; dn < 4; ++dn) accO[dn] *= alpha;

#pragma unroll
      for (int n = 0; n < 4; ++n)
#pragma unroll
        for (int p2 = 0; p2 < 2; ++p2) {
          const unsigned pk = cvt_pk_bf16(st[n][2*p2], st[n][2*p2+1]);
          const int pg = (2*n + (grp >> 1)) ^ swz;
          ((unsigned*)lPw)[lr*32 + pg*4 + (grp & 1)*2 + p2] = pk;
        }

      asm volatile("s_waitcnt lgkmcnt(0)" ::: "memory");

      short8 pa[2];
#pragma unroll
      for (int kk = 0; kk < 2; ++kk)
        pa[kk] = *(const short8*)&lPw[lr*64 + (((kk*4 + grp) ^ swz) * 8)];

#pragma unroll
      for (int dn = 0; dn < 4; ++dn) {
        const int d = dn*16 + lr;
#pragma unroll
        for (int kk = 0; kk < 2; ++kk) {
          const int gp = (kk*4 + grp) ^ (d & 7);
          short8 vf = *(const short8*)&lV[cur][d*64 + gp*8];
          accO[dn] = __builtin_amdgcn_mfma_f32_16x16x32_bf16(vf, pa[kk], accO[dn], 0, 0, 0);
        }
      }
      __syncthreads();
    }

    const float inv = 1.0f / lrow;
    const int token = b*2048 + qw0 + lr;
#pragma unroll
    for (int dn = 0; dn < 4; ++dn)
#pragma unroll
      for (int p2 = 0; p2 < 2; ++p2) {
        const unsigned pk = cvt_pk_bf16(accO[dn][2*p2] * inv, accO[dn][2*p2+1] * inv);
        *(unsigned*)&O[token*1024 + h*64 + dn*16 + grp*4 + 2*p2] = pk;
      }
  }
#undef STAGEKV
}

// ---------------- launcher ----------------
extern "C" void kernel_launch(void* const* d_in, const int* in_sizes, int n_in,
                              void* d_out, int out_size, void* d_ws, size_t ws_size,
                              hipStream_t stream) {
  const float* x  = (const float*)d_in[0];
  const float* Wq = (const float*)d_in[1];
  const float* bq = (const float*)d_in[2];
  const float* Wk = (const float*)d_in[3];
  const float* bk = (const float*)d_in[4];
  const float* Wv = (const float*)d_in[5];
  const float* bv = (const float*)d_in[6];
  const float* Wo = (const float*)d_in[7];
  const float* bo = (const float*)d_in[8];
  float* out = (float*)d_out;

  char* ws = (char*)d_ws;
  u16* xb  = (u16*)(ws + 0);          // [4096][1024] bf16
  u16* wqb = (u16*)(ws + 8388608);
  u16* wkb = (u16*)(ws + 10485760);
  u16* wvb = (u16*)(ws + 12582912);
  u16* wob = (u16*)(ws + 14680064);
  u16* Qb  = (u16*)(ws + 16777216);   // [32][2048][64]
  u16* Kb  = (u16*)(ws + 25165824);   // [32][2048][64]
  u16* Vb  = (u16*)(ws + 33554432);   // [32][64][2048]
  u16* Ab  = (u16*)(ws + 41943040);   // [4096][1024]

  k_cvt_all<<<dim3(8192), 256, 0, stream>>>(x, Wq, Wk, Wv, Wo, xb, wqb, wkb, wvb, wob);

  k_gemm_qkv<<<dim3(768), 256, 0, stream>>>(xb, wqb, wkb, wvb, bq, bk, bv, Qb, Kb, Vb);

  k_attn<<<dim3(512), 256, 0, stream>>>(Qb, Kb, Vb, Ab);

  k_gemm_o<<<dim3(512), 256, 0, stream>>>(Ab, wob, bo, out);
}

// Round 8
// 123.290 us; speedup vs baseline: 1.7460x; 1.0216x over previous
//
#include <hip/hip_runtime.h>

typedef unsigned short u16;
typedef __attribute__((ext_vector_type(8))) short short8;
typedef __attribute__((ext_vector_type(4))) float floatx4;

__device__ __forceinline__ u16 f2bf(float x){
  union { float f; unsigned u; } v; v.f = x;
  unsigned r = v.u + 0x7fffu + ((v.u >> 16) & 1u);
  return (u16)(r >> 16);
}

__device__ __forceinline__ unsigned cvt_pk_bf16(float lo, float hi){
  unsigned r;
  asm("v_cvt_pk_bf16_f32 %0, %1, %2" : "=v"(r) : "v"(lo), "v"(hi));
  return r;
}

__device__ __forceinline__ void gld16(const u16* g, u16* l){
  __builtin_amdgcn_global_load_lds(
      (const __attribute__((address_space(1))) void*)g,
      (__attribute__((address_space(3))) void*)l, 16, 0, 0);
}

// ---------------- fused fp32 -> bf16 convert (x + 4 weights, one launch) -------
__global__ void k_cvt_all(const float* __restrict__ x,
                          const float* __restrict__ wq, const float* __restrict__ wk,
                          const float* __restrict__ wv, const float* __restrict__ wo,
                          u16* __restrict__ xb, u16* __restrict__ wqb, u16* __restrict__ wkb,
                          u16* __restrict__ wvb, u16* __restrict__ wob){
  const int i = blockIdx.x * 256 + threadIdx.x;   // float4 index, total 2097152
  const float* s; u16* d; int off;
  if (i < 1048576) { s = x; d = xb; off = i; }
  else {
    const int j = i - 1048576;
    const int wsel = j >> 18;          // 262144 f4 per weight
    off = j & 262143;
    s = (wsel==0) ? wq : (wsel==1) ? wk : (wsel==2) ? wv : wo;
    d = (wsel==0) ? wqb : (wsel==1) ? wkb : (wsel==2) ? wvb : wob;
  }
  const float4 f = ((const float4*)s)[off];
  unsigned lo = (unsigned)f2bf(f.x) | ((unsigned)f2bf(f.y) << 16);
  unsigned hi = (unsigned)f2bf(f.z) | ((unsigned)f2bf(f.w) << 16);
  ((uint2*)d)[off] = make_uint2(lo, hi);
}

// ---------------- QKV GEMM: 128x128 tile, XCD-chunked placement ----------------
__global__ __launch_bounds__(256) void k_gemm_qkv(
    const u16* __restrict__ A,
    const u16* __restrict__ Wq, const u16* __restrict__ Wk, const u16* __restrict__ Wv,
    const float* __restrict__ bq, const float* __restrict__ bk, const float* __restrict__ bv,
    u16* __restrict__ Qo, u16* __restrict__ Ko, u16* __restrict__ Vo)
{
  const int bid = (int)blockIdx.x;
  const int xcd = bid & 7;
  const int i5  = bid >> 3;                    // 0..95
  const int xb_ = ((xcd >> 2) << 2) + (i5 & 3);        // 0..7
  const int rest = i5 >> 2;                    // 0..23
  const int yb_ = ((xcd & 3) << 3) + (rest & 7);       // 0..31
  const int mode = rest >> 3;                  // 0..2

  const u16* W      = (mode==1) ? Wk : (mode==2) ? Wv : Wq;
  const float* bias = (mode==1) ? bk : (mode==2) ? bv : bq;

  __shared__ u16 lA[2][4096];
  __shared__ u16 lB[2][4096];

  const int tid  = threadIdx.x;
  const int row0 = yb_ * 128;
  const int col0 = xb_ * 128;

  const int srow = tid >> 2;
  const int sgp  = tid & 3;
  const int sgl  = sgp ^ ((srow >> 1) & 3);
  const u16* ga0 = A + (row0 + srow)      * 1024 + sgl * 8;
  const u16* ga1 = A + (row0 + srow + 64) * 1024 + sgl * 8;
  const u16* gb0 = W + (col0 + srow)      * 1024 + sgl * 8;
  const u16* gb1 = W + (col0 + srow + 64) * 1024 + sgl * 8;

  const int l  = tid & 63, w = tid >> 6;
  const int wr = w >> 1,  wc = w & 1;
  const int lr = l & 15,  grp = l >> 4;
  const int sw = (lr >> 1) & 3;
  int aoff[4], boff[4];
#pragma unroll
  for (int m = 0; m < 4; ++m) aoff[m] = (wr*64 + m*16 + lr)*32 + ((grp ^ sw) * 8);
#pragma unroll
  for (int n = 0; n < 4; ++n) boff[n] = (wc*64 + n*16 + lr)*32 + ((grp ^ sw) * 8);

  floatx4 acc[4][4];
#pragma unroll
  for (int m = 0; m < 4; ++m)
#pragma unroll
    for (int n = 0; n < 4; ++n) acc[m][n] = (floatx4){0.f, 0.f, 0.f, 0.f};

#define STAGE(buf, kt_) do { \
    const int k0_ = (kt_) * 32; \
    gld16(ga0 + k0_, &lA[(buf)][tid*8]); \
    gld16(ga1 + k0_, &lA[(buf)][2048 + tid*8]); \
    gld16(gb0 + k0_, &lB[(buf)][tid*8]); \
    gld16(gb1 + k0_, &lB[(buf)][2048 + tid*8]); \
  } while (0)

  STAGE(0, 0);
  __syncthreads();
  for (int kt = 0; kt < 32; ++kt) {
    const int cur = kt & 1;
    if (kt < 31) STAGE(cur ^ 1, kt + 1);
    short8 af[4], bf[4];
#pragma unroll
    for (int m = 0; m < 4; ++m) af[m] = *(const short8*)&lA[cur][aoff[m]];
#pragma unroll
    for (int n = 0; n < 4; ++n) bf[n] = *(const short8*)&lB[cur][boff[n]];
#pragma unroll
    for (int m = 0; m < 4; ++m)
#pragma unroll
      for (int n = 0; n < 4; ++n)
        acc[m][n] = __builtin_amdgcn_mfma_f32_16x16x32_bf16(af[m], bf[n], acc[m][n], 0, 0, 0);
    __syncthreads();
  }
#undef STAGE

  const float sc = (mode == 0) ? 0.18033688011112042f : 1.0f;  // 0.125*log2(e) for Q
  u16* dst = (mode == 0) ? Qo : (mode == 1) ? Ko : Vo;
#pragma unroll
  for (int n = 0; n < 4; ++n) {
    const int cg = col0 + wc*64 + n*16 + lr;
    const float bb = bias[cg];
    const int h = cg >> 6, d = cg & 63;
#pragma unroll
    for (int m = 0; m < 4; ++m) {
#pragma unroll
      for (int j = 0; j < 4; ++j) {
        const int rg = row0 + wr*64 + m*16 + grp*4 + j;
        const int b = rg >> 11, s5 = rg & 2047;
        const float val = (acc[m][n][j] + bb) * sc;
        int idx;
        if (mode == 2) idx = ((b*16 + h)*64 + d)*2048 + s5;
        else           idx = ((b*16 + h)*2048 + s5)*64 + d;
        dst[idx] = f2bf(val);
      }
    }
  }
}

// ---------------- O-proj GEMM: 64x128 tile, 512 blocks (2/CU), XCD-chunked ------
__global__ __launch_bounds__(256) void k_gemm_o(
    const u16* __restrict__ A, const u16* __restrict__ W,
    const float* __restrict__ bias, float* __restrict__ Fo)
{
  const int bid = (int)blockIdx.x;
  const int xcd = bid & 7;
  const int i5  = bid >> 3;                    // 0..63
  const int xb_ = ((xcd >> 2) << 2) + (i5 & 3);        // 0..7
  const int yb_ = ((xcd & 3) << 4) + (i5 >> 2);        // 0..63

  __shared__ u16 lA[2][2048];
  __shared__ u16 lB[2][4096];

  const int tid  = threadIdx.x;
  const int row0 = yb_ * 64;
  const int col0 = xb_ * 128;

  const int srow = tid >> 2;
  const int sgp  = tid & 3;
  const int sgl  = sgp ^ ((srow >> 1) & 3);
  const u16* ga0 = A + (row0 + srow)      * 1024 + sgl * 8;
  const u16* gb0 = W + (col0 + srow)      * 1024 + sgl * 8;
  const u16* gb1 = W + (col0 + srow + 64) * 1024 + sgl * 8;

  const int l  = tid & 63, w = tid >> 6;
  const int wr = w >> 1,  wc = w & 1;
  const int lr = l & 15,  grp = l >> 4;
  const int sw = (lr >> 1) & 3;
  int aoff[2], boff[4];
#pragma unroll
  for (int m = 0; m < 2; ++m) aoff[m] = (wr*32 + m*16 + lr)*32 + ((grp ^ sw) * 8);
#pragma unroll
  for (int n = 0; n < 4; ++n) boff[n] = (wc*64 + n*16 + lr)*32 + ((grp ^ sw) * 8);

  floatx4 acc[2][4];
#pragma unroll
  for (int m = 0; m < 2; ++m)
#pragma unroll
    for (int n = 0; n < 4; ++n) acc[m][n] = (floatx4){0.f, 0.f, 0.f, 0.f};

#define STAGE(buf, kt_) do { \
    const int k0_ = (kt_) * 32; \
    gld16(ga0 + k0_, &lA[(buf)][tid*8]); \
    gld16(gb0 + k0_, &lB[(buf)][tid*8]); \
    gld16(gb1 + k0_, &lB[(buf)][2048 + tid*8]); \
  } while (0)

  STAGE(0, 0);
  __syncthreads();
  for (int kt = 0; kt < 32; ++kt) {
    const int cur = kt & 1;
    if (kt < 31) STAGE(cur ^ 1, kt + 1);
    short8 af[2], bf[4];
#pragma unroll
    for (int m = 0; m < 2; ++m) af[m] = *(const short8*)&lA[cur][aoff[m]];
#pragma unroll
    for (int n = 0; n < 4; ++n) bf[n] = *(const short8*)&lB[cur][boff[n]];
#pragma unroll
    for (int m = 0; m < 2; ++m)
#pragma unroll
      for (int n = 0; n < 4; ++n)
        acc[m][n] = __builtin_amdgcn_mfma_f32_16x16x32_bf16(af[m], bf[n], acc[m][n], 0, 0, 0);
    __syncthreads();
  }
#undef STAGE

#pragma unroll
  for (int n = 0; n < 4; ++n) {
    const int cg = col0 + wc*64 + n*16 + lr;
    const float bb = bias[cg];
#pragma unroll
    for (int m = 0; m < 2; ++m) {
      const int rg = row0 + wr*32 + m*16 + grp*4;
#pragma unroll
      for (int j = 0; j < 4; ++j)
        Fo[(rg + j) * 1024 + cg] = acc[m][n][j] + bb;
    }
  }
}

// ---------------- flash attention v7: pair-unrolled, defer-max, lazy lrow -------
// 512 blocks x 256 thr (4 waves x 16 q). Quad-buffered K/V: 2 tiles per barrier.
__global__ __launch_bounds__(256, 2) void k_attn(
    const u16* __restrict__ Q, const u16* __restrict__ K,
    const u16* __restrict__ V, u16* __restrict__ O)
{
  __shared__ u16 lK[4][4096];     // [64 keys][64 dk] groups-of-8 swizzled, 4 bufs
  __shared__ u16 lV[4][4096];     // [64 dk][64 keys] (V^T) swizzled, 4 bufs
  __shared__ u16 lP[4][1024];     // [wave][16 q][64 keys] (wave-private)

  const int tid = threadIdx.x;
  const int bid = (int)blockIdx.x;
  const int xcd = bid & 7, r = bid >> 3;       // 64 blocks per XCD
  const int bh = xcd * 4 + (r >> 4);           // 4 bh per XCD -> K/V L2-resident
  const int pr = r & 15;                       // pair index: tiles (31-pr, pr)

  const int l = tid & 63, w = tid >> 6;
  const int lr = l & 15, grp = l >> 4;

  const u16* Qh = Q + (size_t)bh * 2048 * 64;
  const u16* Kh = K + (size_t)bh * 2048 * 64;
  const u16* Vh = V + (size_t)bh * 64 * 2048;

  const int srow = tid >> 3, sgp = tid & 7;
  const int sgl = sgp ^ (srow & 7);
  u16* lPw = &lP[w][0];
  const int swz = lr & 7;
  const int b = bh >> 4, h = bh & 15;

#define STAGEKV(buf, kt_) do { \
    gld16(Kh + ((kt_)*64 + srow     )*64 + sgl*8, &lK[(buf)][tid*8]); \
    gld16(Kh + ((kt_)*64 + srow + 32)*64 + sgl*8, &lK[(buf)][2048 + tid*8]); \
    gld16(Vh + (srow     )*2048 + (kt_)*64 + sgl*8, &lV[(buf)][tid*8]); \
    gld16(Vh + (srow + 32)*2048 + (kt_)*64 + sgl*8, &lV[(buf)][2048 + tid*8]); \
  } while (0)

#pragma unroll
  for (int pass = 0; pass < 2; ++pass) {
    const int qt = pass ? pr : (31 - pr);
    const int qw0 = qt * 64 + w * 16;
    const int nkt = qt + 1;

    short8 qf[2];
#pragma unroll
    for (int kk = 0; kk < 2; ++kk)
      qf[kk] = *(const short8*)(Qh + (qw0 + lr)*64 + kk*32 + grp*8);

    floatx4 accO[4];               // O^T: [d=dn*16+grp*4+j][q=lr]
    float mrow = -1e30f, lrow = 0.f;   // lrow = per-lane PARTIAL (this lane's keys)
#pragma unroll
    for (int dn = 0; dn < 4; ++dn) accO[dn] = (floatx4){0.f, 0.f, 0.f, 0.f};

    STAGEKV(0, 0);
    if (nkt > 1) STAGEKV(1, 1);
    __syncthreads();

    for (int kt2 = 0; kt2 < nkt; kt2 += 2) {
      if (kt2 + 2 < nkt) STAGEKV((kt2 + 2) & 3, kt2 + 2);
      if (kt2 + 3 < nkt) STAGEKV((kt2 + 3) & 3, kt2 + 3);

#pragma unroll
      for (int half = 0; half < 2; ++half) {
        const int kt = kt2 + half;
        if (half == 1 && kt >= nkt) break;     // uniform across block
        const int cur = kt & 3;
        const int kb = kt * 64;

        // S^T = K Q^T : st[n] reg j -> key = kb+n*16+grp*4+j, query = qw0+lr
        floatx4 st[4];
#pragma unroll
        for (int n = 0; n < 4; ++n) st[n] = (floatx4){0.f, 0.f, 0.f, 0.f};
#pragma unroll
        for (int n = 0; n < 4; ++n) {
          const int key = n*16 + lr;
#pragma unroll
          for (int kk = 0; kk < 2; ++kk) {
            const int gp = (kk*4 + grp) ^ (key & 7);
            short8 kf = *(const short8*)&lK[cur][key*64 + gp*8];
            st[n] = __builtin_amdgcn_mfma_f32_16x16x32_bf16(kf, qf[kk], st[n], 0, 0, 0);
          }
        }

        // causal mask (only diagonal tile kt==qt is partial)
        const int lim = qw0 + lr - kb;
        if (63 > lim) {
#pragma unroll
          for (int n = 0; n < 4; ++n)
#pragma unroll
            for (int j = 0; j < 4; ++j)
              if (n*16 + grp*4 + j > lim) st[n][j] = -1e30f;
        }

        // defer-max online softmax: local max; reduce+rescale only if it grew
        float mt = st[0][0];
#pragma unroll
        for (int n = 0; n < 4; ++n)
#pragma unroll
          for (int j = 0; j < 4; ++j) mt = fmaxf(mt, st[n][j]);
        if (!__all(mt <= mrow)) {
          float mg = fmaxf(mt, __shfl_xor(mt, 16));
          mg = fmaxf(mg, __shfl_xor(mg, 32));
          const float mn = fmaxf(mrow, mg);
          const float alpha = exp2f(mrow - mn);
          mrow = mn;
          lrow *= alpha;
#pragma unroll
          for (int dn = 0; dn < 4; ++dn) accO[dn] *= alpha;
        }
        float ps = 0.f;
#pragma unroll
        for (int n = 0; n < 4; ++n)
#pragma unroll
          for (int j = 0; j < 4; ++j) {
            const float p = exp2f(st[n][j] - mrow);
            st[n][j] = p;
            ps += p;
          }
        lrow += ps;                  // per-lane partial; reduced once in epilogue

        // pack P -> wave-private LDS [q][key], swizzled groups-of-8
#pragma unroll
        for (int n = 0; n < 4; ++n)
#pragma unroll
          for (int p2 = 0; p2 < 2; ++p2) {
            const unsigned pk = cvt_pk_bf16(st[n][2*p2], st[n][2*p2+1]);
            const int pg = (2*n + (grp >> 1)) ^ swz;
            ((unsigned*)lPw)[lr*32 + pg*4 + (grp & 1)*2 + p2] = pk;
          }

        asm volatile("s_waitcnt lgkmcnt(0)" ::: "memory");

        short8 pa[2];
#pragma unroll
        for (int kk = 0; kk < 2; ++kk)
          pa[kk] = *(const short8*)&lPw[lr*64 + (((kk*4 + grp) ^ swz) * 8)];

        // O^T += V^T P
#pragma unroll
        for (int dn = 0; dn < 4; ++dn) {
          const int d = dn*16 + lr;
#pragma unroll
          for (int kk = 0; kk < 2; ++kk) {
            const int gp = (kk*4 + grp) ^ (d & 7);
            short8 vf = *(const short8*)&lV[cur][d*64 + gp*8];
            accO[dn] = __builtin_amdgcn_mfma_f32_16x16x32_bf16(vf, pa[kk], accO[dn], 0, 0, 0);
          }
        }
      }
      __syncthreads();               // pair's buffers free; staged pair landed
    }

    // epilogue: reduce lrow across the q-row's 4 lanes, write O^T
    float lt = lrow + __shfl_xor(lrow, 16);
    lt += __shfl_xor(lt, 32);
    const float inv = 1.0f / lt;
    const int token = b*2048 + qw0 + lr;
#pragma unroll
    for (int dn = 0; dn < 4; ++dn)
#pragma unroll
      for (int p2 = 0; p2 < 2; ++p2) {
        const unsigned pk = cvt_pk_bf16(accO[dn][2*p2] * inv, accO[dn][2*p2+1] * inv);
        *(unsigned*)&O[token*1024 + h*64 + dn*16 + grp*4 + 2*p2] = pk;
      }
  }
#undef STAGEKV
}

// ---------------- launcher ----------------
extern "C" void kernel_launch(void* const* d_in, const int* in_sizes, int n_in,
                              void* d_out, int out_size, void* d_ws, size_t ws_size,
                              hipStream_t stream) {
  const float* x  = (const float*)d_in[0];
  const float* Wq = (const float*)d_in[1];
  const float* bq = (const float*)d_in[2];
  const float* Wk = (const float*)d_in[3];
  const float* bk = (const float*)d_in[4];
  const float* Wv = (const float*)d_in[5];
  const float* bv = (const float*)d_in[6];
  const float* Wo = (const float*)d_in[7];
  const float* bo = (const float*)d_in[8];
  float* out = (float*)d_out;

  char* ws = (char*)d_ws;
  u16* xb  = (u16*)(ws + 0);          // [4096][1024] bf16
  u16* wqb = (u16*)(ws + 8388608);
  u16* wkb = (u16*)(ws + 10485760);
  u16* wvb = (u16*)(ws + 12582912);
  u16* wob = (u16*)(ws + 14680064);
  u16* Qb  = (u16*)(ws + 16777216);   // [32][2048][64]
  u16* Kb  = (u16*)(ws + 25165824);   // [32][2048][64]
  u16* Vb  = (u16*)(ws + 33554432);   // [32][64][2048]
  u16* Ab  = (u16*)(ws + 41943040);   // [4096][1024]

  k_cvt_all<<<dim3(8192), 256, 0, stream>>>(x, Wq, Wk, Wv, Wo, xb, wqb, wkb, wvb, wob);

  k_gemm_qkv<<<dim3(768), 256, 0, stream>>>(xb, wqb, wkb, wvb, bq, bk, bv, Qb, Kb, Vb);

  k_attn<<<dim3(512), 256, 0, stream>>>(Qb, Kb, Vb, Ab);

  k_gemm_o<<<dim3(512), 256, 0, stream>>>(Ab, wob, bo, out);
}

// Round 9
// 121.598 us; speedup vs baseline: 1.7703x; 1.0139x over previous
//
#include <hip/hip_runtime.h>

typedef unsigned short u16;
typedef __attribute__((ext_vector_type(8))) short short8;
typedef __attribute__((ext_vector_type(4))) float floatx4;

__device__ __forceinline__ u16 f2bf(float x){
  union { float f; unsigned u; } v; v.f = x;
  unsigned r = v.u + 0x7fffu + ((v.u >> 16) & 1u);
  return (u16)(r >> 16);
}

__device__ __forceinline__ unsigned cvt_pk_bf16(float lo, float hi){
  unsigned r;
  asm("v_cvt_pk_bf16_f32 %0, %1, %2" : "=v"(r) : "v"(lo), "v"(hi));
  return r;
}

__device__ __forceinline__ void gld16(const u16* g, u16* l){
  __builtin_amdgcn_global_load_lds(
      (const __attribute__((address_space(1))) void*)g,
      (__attribute__((address_space(3))) void*)l, 16, 0, 0);
}

// counted-vmcnt barrier: previous tile's loads landed, newest stay in flight
#define WAIT_BAR_V4() asm volatile("s_waitcnt vmcnt(4) lgkmcnt(0)\ns_barrier" ::: "memory")
#define WAIT_BAR_V3() asm volatile("s_waitcnt vmcnt(3) lgkmcnt(0)\ns_barrier" ::: "memory")
#define WAIT_BAR_V0() asm volatile("s_waitcnt vmcnt(0) lgkmcnt(0)\ns_barrier" ::: "memory")

// ---------------- fused fp32 -> bf16 convert (x + 4 weights, one launch) -------
__global__ void k_cvt_all(const float* __restrict__ x,
                          const float* __restrict__ wq, const float* __restrict__ wk,
                          const float* __restrict__ wv, const float* __restrict__ wo,
                          u16* __restrict__ xb, u16* __restrict__ wqb, u16* __restrict__ wkb,
                          u16* __restrict__ wvb, u16* __restrict__ wob){
  const int i = blockIdx.x * 256 + threadIdx.x;   // float4 index, total 2097152
  const float* s; u16* d; int off;
  if (i < 1048576) { s = x; d = xb; off = i; }
  else {
    const int j = i - 1048576;
    const int wsel = j >> 18;          // 262144 f4 per weight
    off = j & 262143;
    s = (wsel==0) ? wq : (wsel==1) ? wk : (wsel==2) ? wv : wo;
    d = (wsel==0) ? wqb : (wsel==1) ? wkb : (wsel==2) ? wvb : wob;
  }
  const float4 f = ((const float4*)s)[off];
  unsigned lo = (unsigned)f2bf(f.x) | ((unsigned)f2bf(f.y) << 16);
  unsigned hi = (unsigned)f2bf(f.z) | ((unsigned)f2bf(f.w) << 16);
  ((uint2*)d)[off] = make_uint2(lo, hi);
}

// ---------------- QKV GEMM: 128x128 tile, XCD-chunked, triple-buffered ----------
__global__ __launch_bounds__(256) void k_gemm_qkv(
    const u16* __restrict__ A,
    const u16* __restrict__ Wq, const u16* __restrict__ Wk, const u16* __restrict__ Wv,
    const float* __restrict__ bq, const float* __restrict__ bk, const float* __restrict__ bv,
    u16* __restrict__ Qo, u16* __restrict__ Ko, u16* __restrict__ Vo)
{
  const int bid = (int)blockIdx.x;
  const int xcd = bid & 7;
  const int i5  = bid >> 3;                    // 0..95
  const int xb_ = ((xcd >> 2) << 2) + (i5 & 3);        // 0..7
  const int rest = i5 >> 2;                    // 0..23
  const int yb_ = ((xcd & 3) << 3) + (rest & 7);       // 0..31
  const int mode = rest >> 3;                  // 0..2

  const u16* W      = (mode==1) ? Wk : (mode==2) ? Wv : Wq;
  const float* bias = (mode==1) ? bk : (mode==2) ? bv : bq;

  __shared__ u16 lA[3][4096];   // [128 rows][32 k], triple-buffered
  __shared__ u16 lB[3][4096];

  const int tid  = threadIdx.x;
  const int row0 = yb_ * 128;
  const int col0 = xb_ * 128;

  const int srow = tid >> 2;
  const int sgp  = tid & 3;
  const int sgl  = sgp ^ ((srow >> 1) & 3);
  const u16* ga0 = A + (row0 + srow)      * 1024 + sgl * 8;
  const u16* ga1 = A + (row0 + srow + 64) * 1024 + sgl * 8;
  const u16* gb0 = W + (col0 + srow)      * 1024 + sgl * 8;
  const u16* gb1 = W + (col0 + srow + 64) * 1024 + sgl * 8;

  const int l  = tid & 63, w = tid >> 6;
  const int wr = w >> 1,  wc = w & 1;
  const int lr = l & 15,  grp = l >> 4;
  const int sw = (lr >> 1) & 3;
  int aoff[4], boff[4];
#pragma unroll
  for (int m = 0; m < 4; ++m) aoff[m] = (wr*64 + m*16 + lr)*32 + ((grp ^ sw) * 8);
#pragma unroll
  for (int n = 0; n < 4; ++n) boff[n] = (wc*64 + n*16 + lr)*32 + ((grp ^ sw) * 8);

  floatx4 acc[4][4];
#pragma unroll
  for (int m = 0; m < 4; ++m)
#pragma unroll
    for (int n = 0; n < 4; ++n) acc[m][n] = (floatx4){0.f, 0.f, 0.f, 0.f};

#define STAGE(buf, kt_) do { \
    const int k0_ = (kt_) * 32; \
    gld16(ga0 + k0_, &lA[(buf)][tid*8]); \
    gld16(ga1 + k0_, &lA[(buf)][2048 + tid*8]); \
    gld16(gb0 + k0_, &lB[(buf)][tid*8]); \
    gld16(gb1 + k0_, &lB[(buf)][2048 + tid*8]); \
  } while (0)

  STAGE(0, 0);
  STAGE(1, 1);
  asm volatile("s_waitcnt vmcnt(4)\ns_barrier" ::: "memory");

  for (int kt = 0; kt < 32; ++kt) {
    const int cur = kt % 3;
    const bool st2 = (kt + 2 < 32);
    if (st2) STAGE((kt + 2) % 3, kt + 2);
    short8 af[4], bf[4];
#pragma unroll
    for (int m = 0; m < 4; ++m) af[m] = *(const short8*)&lA[cur][aoff[m]];
#pragma unroll
    for (int n = 0; n < 4; ++n) bf[n] = *(const short8*)&lB[cur][boff[n]];
#pragma unroll
    for (int m = 0; m < 4; ++m)
#pragma unroll
      for (int n = 0; n < 4; ++n)
        acc[m][n] = __builtin_amdgcn_mfma_f32_16x16x32_bf16(af[m], bf[n], acc[m][n], 0, 0, 0);
    if (st2) WAIT_BAR_V4(); else WAIT_BAR_V0();
  }
#undef STAGE

  const float sc = (mode == 0) ? 0.18033688011112042f : 1.0f;  // 0.125*log2(e) for Q
  u16* dst = (mode == 0) ? Qo : (mode == 1) ? Ko : Vo;
#pragma unroll
  for (int n = 0; n < 4; ++n) {
    const int cg = col0 + wc*64 + n*16 + lr;
    const float bb = bias[cg];
    const int h = cg >> 6, d = cg & 63;
#pragma unroll
    for (int m = 0; m < 4; ++m) {
#pragma unroll
      for (int j = 0; j < 4; ++j) {
        const int rg = row0 + wr*64 + m*16 + grp*4 + j;
        const int b = rg >> 11, s5 = rg & 2047;
        const float val = (acc[m][n][j] + bb) * sc;
        int idx;
        if (mode == 2) idx = ((b*16 + h)*64 + d)*2048 + s5;
        else           idx = ((b*16 + h)*2048 + s5)*64 + d;
        dst[idx] = f2bf(val);
      }
    }
  }
}

// ---------------- O-proj GEMM: 64x128 tile, XCD-chunked, triple-buffered --------
__global__ __launch_bounds__(256) void k_gemm_o(
    const u16* __restrict__ A, const u16* __restrict__ W,
    const float* __restrict__ bias, float* __restrict__ Fo)
{
  const int bid = (int)blockIdx.x;
  const int xcd = bid & 7;
  const int i5  = bid >> 3;                    // 0..63
  const int xb_ = ((xcd >> 2) << 2) + (i5 & 3);        // 0..7
  const int yb_ = ((xcd & 3) << 4) + (i5 >> 2);        // 0..63

  __shared__ u16 lA[3][2048];
  __shared__ u16 lB[3][4096];

  const int tid  = threadIdx.x;
  const int row0 = yb_ * 64;
  const int col0 = xb_ * 128;

  const int srow = tid >> 2;
  const int sgp  = tid & 3;
  const int sgl  = sgp ^ ((srow >> 1) & 3);
  const u16* ga0 = A + (row0 + srow)      * 1024 + sgl * 8;
  const u16* gb0 = W + (col0 + srow)      * 1024 + sgl * 8;
  const u16* gb1 = W + (col0 + srow + 64) * 1024 + sgl * 8;

  const int l  = tid & 63, w = tid >> 6;
  const int wr = w >> 1,  wc = w & 1;
  const int lr = l & 15,  grp = l >> 4;
  const int sw = (lr >> 1) & 3;
  int aoff[2], boff[4];
#pragma unroll
  for (int m = 0; m < 2; ++m) aoff[m] = (wr*32 + m*16 + lr)*32 + ((grp ^ sw) * 8);
#pragma unroll
  for (int n = 0; n < 4; ++n) boff[n] = (wc*64 + n*16 + lr)*32 + ((grp ^ sw) * 8);

  floatx4 acc[2][4];
#pragma unroll
  for (int m = 0; m < 2; ++m)
#pragma unroll
    for (int n = 0; n < 4; ++n) acc[m][n] = (floatx4){0.f, 0.f, 0.f, 0.f};

#define STAGE(buf, kt_) do { \
    const int k0_ = (kt_) * 32; \
    gld16(ga0 + k0_, &lA[(buf)][tid*8]); \
    gld16(gb0 + k0_, &lB[(buf)][tid*8]); \
    gld16(gb1 + k0_, &lB[(buf)][2048 + tid*8]); \
  } while (0)

  STAGE(0, 0);
  STAGE(1, 1);
  asm volatile("s_waitcnt vmcnt(3)\ns_barrier" ::: "memory");

  for (int kt = 0; kt < 32; ++kt) {
    const int cur = kt % 3;
    const bool st2 = (kt + 2 < 32);
    if (st2) STAGE((kt + 2) % 3, kt + 2);
    short8 af[2], bf[4];
#pragma unroll
    for (int m = 0; m < 2; ++m) af[m] = *(const short8*)&lA[cur][aoff[m]];
#pragma unroll
    for (int n = 0; n < 4; ++n) bf[n] = *(const short8*)&lB[cur][boff[n]];
#pragma unroll
    for (int m = 0; m < 2; ++m)
#pragma unroll
      for (int n = 0; n < 4; ++n)
        acc[m][n] = __builtin_amdgcn_mfma_f32_16x16x32_bf16(af[m], bf[n], acc[m][n], 0, 0, 0);
    if (st2) WAIT_BAR_V3(); else WAIT_BAR_V0();
  }
#undef STAGE

#pragma unroll
  for (int n = 0; n < 4; ++n) {
    const int cg = col0 + wc*64 + n*16 + lr;
    const float bb = bias[cg];
#pragma unroll
    for (int m = 0; m < 2; ++m) {
      const int rg = row0 + wr*32 + m*16 + grp*4;
#pragma unroll
      for (int j = 0; j < 4; ++j)
        Fo[(rg + j) * 1024 + cg] = acc[m][n][j] + bb;
    }
  }
}

// ---------------- flash attention v8: triple-buffer, distance-2 prefetch -------
// 512 blocks x 256 thr (4 waves x 16 q). One counted-vmcnt barrier per phase.
__global__ __launch_bounds__(256, 2) void k_attn(
    const u16* __restrict__ Q, const u16* __restrict__ K,
    const u16* __restrict__ V, u16* __restrict__ O)
{
  __shared__ u16 lK[3][4096];     // [64 keys][64 dk] groups-of-8 swizzled, 3 bufs
  __shared__ u16 lV[3][4096];     // [64 dk][64 keys] (V^T) swizzled, 3 bufs
  __shared__ u16 lP[4][1024];     // [wave][16 q][64 keys] (wave-private)

  const int tid = threadIdx.x;
  const int bid = (int)blockIdx.x;
  const int xcd = bid & 7, r = bid >> 3;       // 64 blocks per XCD
  const int bh = xcd * 4 + (r >> 4);           // 4 bh per XCD -> K/V L2-resident
  const int pr = r & 15;                       // pair index: tiles (31-pr, pr)

  const int l = tid & 63, w = tid >> 6;
  const int lr = l & 15, grp = l >> 4;

  const u16* Qh = Q + (size_t)bh * 2048 * 64;
  const u16* Kh = K + (size_t)bh * 2048 * 64;
  const u16* Vh = V + (size_t)bh * 64 * 2048;

  const int srow = tid >> 3, sgp = tid & 7;
  const int sgl = sgp ^ (srow & 7);
  u16* lPw = &lP[w][0];
  const int swz = lr & 7;
  const int b = bh >> 4, h = bh & 15;

#define STAGEKV(buf, kt_) do { \
    gld16(Kh + ((kt_)*64 + srow     )*64 + sgl*8, &lK[(buf)][tid*8]); \
    gld16(Kh + ((kt_)*64 + srow + 32)*64 + sgl*8, &lK[(buf)][2048 + tid*8]); \
    gld16(Vh + (srow     )*2048 + (kt_)*64 + sgl*8, &lV[(buf)][tid*8]); \
    gld16(Vh + (srow + 32)*2048 + (kt_)*64 + sgl*8, &lV[(buf)][2048 + tid*8]); \
  } while (0)

#pragma unroll
  for (int pass = 0; pass < 2; ++pass) {
    const int qt = pass ? pr : (31 - pr);
    const int qw0 = qt * 64 + w * 16;
    const int nkt = qt + 1;

    short8 qf[2];
#pragma unroll
    for (int kk = 0; kk < 2; ++kk)
      qf[kk] = *(const short8*)(Qh + (qw0 + lr)*64 + kk*32 + grp*8);

    floatx4 accO[4];               // O^T: [d=dn*16+grp*4+j][q=lr]
    float mrow = -1e30f, lrow = 0.f;   // lrow = per-lane PARTIAL (this lane's keys)
#pragma unroll
    for (int dn = 0; dn < 4; ++dn) accO[dn] = (floatx4){0.f, 0.f, 0.f, 0.f};

    STAGEKV(0, 0);
    if (nkt > 1) {
      STAGEKV(1, 1);
      asm volatile("s_waitcnt vmcnt(4)\ns_barrier" ::: "memory");
    } else {
      asm volatile("s_waitcnt vmcnt(0)\ns_barrier" ::: "memory");
    }

    for (int kt = 0; kt < nkt; ++kt) {
      const int cur = kt % 3;
      const bool st2 = (kt + 2 < nkt);
      if (st2) STAGEKV((kt + 2) % 3, kt + 2);
      const int kb = kt * 64;

      // S^T = K Q^T : st[n] reg j -> key = kb+n*16+grp*4+j, query = qw0+lr
      floatx4 st[4];
#pragma unroll
      for (int n = 0; n < 4; ++n) st[n] = (floatx4){0.f, 0.f, 0.f, 0.f};
#pragma unroll
      for (int n = 0; n < 4; ++n) {
        const int key = n*16 + lr;
#pragma unroll
        for (int kk = 0; kk < 2; ++kk) {
          const int gp = (kk*4 + grp) ^ (key & 7);
          short8 kf = *(const short8*)&lK[cur][key*64 + gp*8];
          st[n] = __builtin_amdgcn_mfma_f32_16x16x32_bf16(kf, qf[kk], st[n], 0, 0, 0);
        }
      }

      // causal mask (only diagonal tile kt==qt is partial)
      const int lim = qw0 + lr - kb;
      if (63 > lim) {
#pragma unroll
        for (int n = 0; n < 4; ++n)
#pragma unroll
          for (int j = 0; j < 4; ++j)
            if (n*16 + grp*4 + j > lim) st[n][j] = -1e30f;
      }

      // defer-max online softmax: local max; reduce+rescale only if it grew
      float mt = st[0][0];
#pragma unroll
      for (int n = 0; n < 4; ++n)
#pragma unroll
        for (int j = 0; j < 4; ++j) mt = fmaxf(mt, st[n][j]);
      if (!__all(mt <= mrow)) {
        float mg = fmaxf(mt, __shfl_xor(mt, 16));
        mg = fmaxf(mg, __shfl_xor(mg, 32));
        const float mn = fmaxf(mrow, mg);
        const float alpha = exp2f(mrow - mn);
        mrow = mn;
        lrow *= alpha;
#pragma unroll
        for (int dn = 0; dn < 4; ++dn) accO[dn] *= alpha;
      }
      float ps = 0.f;
#pragma unroll
      for (int n = 0; n < 4; ++n)
#pragma unroll
        for (int j = 0; j < 4; ++j) {
          const float p = exp2f(st[n][j] - mrow);
          st[n][j] = p;
          ps += p;
        }
      lrow += ps;                  // per-lane partial; reduced once in epilogue

      // pack P -> wave-private LDS [q][key], swizzled groups-of-8
#pragma unroll
      for (int n = 0; n < 4; ++n)
#pragma unroll
        for (int p2 = 0; p2 < 2; ++p2) {
          const unsigned pk = cvt_pk_bf16(st[n][2*p2], st[n][2*p2+1]);
          const int pg = (2*n + (grp >> 1)) ^ swz;
          ((unsigned*)lPw)[lr*32 + pg*4 + (grp & 1)*2 + p2] = pk;
        }

      asm volatile("s_waitcnt lgkmcnt(0)" ::: "memory");

      short8 pa[2];
#pragma unroll
      for (int kk = 0; kk < 2; ++kk)
        pa[kk] = *(const short8*)&lPw[lr*64 + (((kk*4 + grp) ^ swz) * 8)];

      // O^T += V^T P
#pragma unroll
      for (int dn = 0; dn < 4; ++dn) {
        const int d = dn*16 + lr;
#pragma unroll
        for (int kk = 0; kk < 2; ++kk) {
          const int gp = (kk*4 + grp) ^ (d & 7);
          short8 vf = *(const short8*)&lV[cur][d*64 + gp*8];
          accO[dn] = __builtin_amdgcn_mfma_f32_16x16x32_bf16(vf, pa[kk], accO[dn], 0, 0, 0);
        }
      }

      if (st2) WAIT_BAR_V4(); else WAIT_BAR_V0();
    }

    // epilogue: reduce lrow across the q-row's 4 lanes, write O^T
    float lt = lrow + __shfl_xor(lrow, 16);
    lt += __shfl_xor(lt, 32);
    const float inv = 1.0f / lt;
    const int token = b*2048 + qw0 + lr;
#pragma unroll
    for (int dn = 0; dn < 4; ++dn)
#pragma unroll
      for (int p2 = 0; p2 < 2; ++p2) {
        const unsigned pk = cvt_pk_bf16(accO[dn][2*p2] * inv, accO[dn][2*p2+1] * inv);
        *(unsigned*)&O[token*1024 + h*64 + dn*16 + grp*4 + 2*p2] = pk;
      }
  }
#undef STAGEKV
}

// ---------------- launcher ----------------
extern "C" void kernel_launch(void* const* d_in, const int* in_sizes, int n_in,
                              void* d_out, int out_size, void* d_ws, size_t ws_size,
                              hipStream_t stream) {
  const float* x  = (const float*)d_in[0];
  const float* Wq = (const float*)d_in[1];
  const float* bq = (const float*)d_in[2];
  const float* Wk = (const float*)d_in[3];
  const float* bk = (const float*)d_in[4];
  const float* Wv = (const float*)d_in[5];
  const float* bv = (const float*)d_in[6];
  const float* Wo = (const float*)d_in[7];
  const float* bo = (const float*)d_in[8];
  float* out = (float*)d_out;

  char* ws = (char*)d_ws;
  u16* xb  = (u16*)(ws + 0);          // [4096][1024] bf16
  u16* wqb = (u16*)(ws + 8388608);
  u16* wkb = (u16*)(ws + 10485760);
  u16* wvb = (u16*)(ws + 12582912);
  u16* wob = (u16*)(ws + 14680064);
  u16* Qb  = (u16*)(ws + 16777216);   // [32][2048][64]
  u16* Kb  = (u16*)(ws + 25165824);   // [32][2048][64]
  u16* Vb  = (u16*)(ws + 33554432);   // [32][64][2048]
  u16* Ab  = (u16*)(ws + 41943040);   // [4096][1024]

  k_cvt_all<<<dim3(8192), 256, 0, stream>>>(x, Wq, Wk, Wv, Wo, xb, wqb, wkb, wvb, wob);

  k_gemm_qkv<<<dim3(768), 256, 0, stream>>>(xb, wqb, wkb, wvb, bq, bk, bv, Qb, Kb, Vb);

  k_attn<<<dim3(512), 256, 0, stream>>>(Qb, Kb, Vb, Ab);

  k_gemm_o<<<dim3(512), 256, 0, stream>>>(Ab, wob, bo, out);
}

// Round 10
// 112.898 us; speedup vs baseline: 1.9067x; 1.0771x over previous
//
#include <hip/hip_runtime.h>

typedef unsigned short u16;
typedef __attribute__((ext_vector_type(8))) short short8;
typedef __attribute__((ext_vector_type(4))) float floatx4;

__device__ __forceinline__ u16 f2bf(float x){
  union { float f; unsigned u; } v; v.f = x;
  unsigned r = v.u + 0x7fffu + ((v.u >> 16) & 1u);
  return (u16)(r >> 16);
}

__device__ __forceinline__ unsigned cvt_pk_bf16(float lo, float hi){
  unsigned r;
  asm("v_cvt_pk_bf16_f32 %0, %1, %2" : "=v"(r) : "v"(lo), "v"(hi));
  return r;
}

// raw v_exp_f32: args here are always <= 0; underflow -> 0 (wanted). No OCML fixup.
__device__ __forceinline__ float exp2_raw(float x){
  float r;
  asm("v_exp_f32 %0, %1" : "=v"(r) : "v"(x));
  return r;
}

__device__ __forceinline__ void gld16(const u16* g, u16* l){
  __builtin_amdgcn_global_load_lds(
      (const __attribute__((address_space(1))) void*)g,
      (__attribute__((address_space(3))) void*)l, 16, 0, 0);
}

// counted-vmcnt barrier: previous tile's loads landed, newest stay in flight
#define WAIT_BAR_V4() asm volatile("s_waitcnt vmcnt(4) lgkmcnt(0)\ns_barrier" ::: "memory")
#define WAIT_BAR_V3() asm volatile("s_waitcnt vmcnt(3) lgkmcnt(0)\ns_barrier" ::: "memory")
#define WAIT_BAR_V0() asm volatile("s_waitcnt vmcnt(0) lgkmcnt(0)\ns_barrier" ::: "memory")

// ---------------- fused fp32 -> bf16 convert (x + 4 weights, one launch) -------
__global__ void k_cvt_all(const float* __restrict__ x,
                          const float* __restrict__ wq, const float* __restrict__ wk,
                          const float* __restrict__ wv, const float* __restrict__ wo,
                          u16* __restrict__ xb, u16* __restrict__ wqb, u16* __restrict__ wkb,
                          u16* __restrict__ wvb, u16* __restrict__ wob){
  const int i = blockIdx.x * 256 + threadIdx.x;   // float4 index, total 2097152
  const float* s; u16* d; int off;
  if (i < 1048576) { s = x; d = xb; off = i; }
  else {
    const int j = i - 1048576;
    const int wsel = j >> 18;          // 262144 f4 per weight
    off = j & 262143;
    s = (wsel==0) ? wq : (wsel==1) ? wk : (wsel==2) ? wv : wo;
    d = (wsel==0) ? wqb : (wsel==1) ? wkb : (wsel==2) ? wvb : wob;
  }
  const float4 f = ((const float4*)s)[off];
  unsigned lo = (unsigned)f2bf(f.x) | ((unsigned)f2bf(f.y) << 16);
  unsigned hi = (unsigned)f2bf(f.z) | ((unsigned)f2bf(f.w) << 16);
  ((uint2*)d)[off] = make_uint2(lo, hi);
}

// ---------------- QKV GEMM: 128x128 tile, XCD-chunked, triple-buffered ----------
// unrolled-by-3 so LDS buffer index is compile-time (imm offsets, no addr VALU)
__global__ __launch_bounds__(256) void k_gemm_qkv(
    const u16* __restrict__ A,
    const u16* __restrict__ Wq, const u16* __restrict__ Wk, const u16* __restrict__ Wv,
    const float* __restrict__ bq, const float* __restrict__ bk, const float* __restrict__ bv,
    u16* __restrict__ Qo, u16* __restrict__ Ko, u16* __restrict__ Vo)
{
  const int bid = (int)blockIdx.x;
  const int xcd = bid & 7;
  const int i5  = bid >> 3;                    // 0..95
  const int xb_ = ((xcd >> 2) << 2) + (i5 & 3);        // 0..7
  const int rest = i5 >> 2;                    // 0..23
  const int yb_ = ((xcd & 3) << 3) + (rest & 7);       // 0..31
  const int mode = rest >> 3;                  // 0..2

  const u16* W      = (mode==1) ? Wk : (mode==2) ? Wv : Wq;
  const float* bias = (mode==1) ? bk : (mode==2) ? bv : bq;

  __shared__ u16 lA[3][4096];   // [128 rows][32 k], triple-buffered
  __shared__ u16 lB[3][4096];

  const int tid  = threadIdx.x;
  const int row0 = yb_ * 128;
  const int col0 = xb_ * 128;

  const int srow = tid >> 2;
  const int sgp  = tid & 3;
  const int sgl  = sgp ^ ((srow >> 1) & 3);
  const u16* ga0 = A + (row0 + srow)      * 1024 + sgl * 8;
  const u16* ga1 = A + (row0 + srow + 64) * 1024 + sgl * 8;
  const u16* gb0 = W + (col0 + srow)      * 1024 + sgl * 8;
  const u16* gb1 = W + (col0 + srow + 64) * 1024 + sgl * 8;

  const int l  = tid & 63, w = tid >> 6;
  const int wr = w >> 1,  wc = w & 1;
  const int lr = l & 15,  grp = l >> 4;
  const int sw = (lr >> 1) & 3;
  int aoff[4], boff[4];
#pragma unroll
  for (int m = 0; m < 4; ++m) aoff[m] = (wr*64 + m*16 + lr)*32 + ((grp ^ sw) * 8);
#pragma unroll
  for (int n = 0; n < 4; ++n) boff[n] = (wc*64 + n*16 + lr)*32 + ((grp ^ sw) * 8);

  floatx4 acc[4][4];
#pragma unroll
  for (int m = 0; m < 4; ++m)
#pragma unroll
    for (int n = 0; n < 4; ++n) acc[m][n] = (floatx4){0.f, 0.f, 0.f, 0.f};

#define STAGE(buf, kt_) do { \
    const int k0_ = (kt_) * 32; \
    gld16(ga0 + k0_, &lA[(buf)][tid*8]); \
    gld16(ga1 + k0_, &lA[(buf)][2048 + tid*8]); \
    gld16(gb0 + k0_, &lB[(buf)][tid*8]); \
    gld16(gb1 + k0_, &lB[(buf)][2048 + tid*8]); \
  } while (0)

  STAGE(0, 0);
  STAGE(1, 1);
  asm volatile("s_waitcnt vmcnt(4)\ns_barrier" ::: "memory");

  for (int kt0 = 0; kt0 < 32; kt0 += 3) {
#pragma unroll
    for (int i = 0; i < 3; ++i) {              // i == buffer index (compile-time)
      const int kt = kt0 + i;
      if (kt >= 32) break;
      const bool st2 = (kt + 2 < 32);
      if (st2) STAGE((i + 2) % 3, kt + 2);
      short8 af[4], bf[4];
#pragma unroll
      for (int m = 0; m < 4; ++m) af[m] = *(const short8*)&lA[i][aoff[m]];
#pragma unroll
      for (int n = 0; n < 4; ++n) bf[n] = *(const short8*)&lB[i][boff[n]];
#pragma unroll
      for (int m = 0; m < 4; ++m)
#pragma unroll
        for (int n = 0; n < 4; ++n)
          acc[m][n] = __builtin_amdgcn_mfma_f32_16x16x32_bf16(af[m], bf[n], acc[m][n], 0, 0, 0);
      if (st2) WAIT_BAR_V4(); else WAIT_BAR_V0();
    }
  }
#undef STAGE

  const float sc = (mode == 0) ? 0.18033688011112042f : 1.0f;  // 0.125*log2(e) for Q
  u16* dst = (mode == 0) ? Qo : (mode == 1) ? Ko : Vo;
#pragma unroll
  for (int n = 0; n < 4; ++n) {
    const int cg = col0 + wc*64 + n*16 + lr;
    const float bb = bias[cg];
    const int h = cg >> 6, d = cg & 63;
#pragma unroll
    for (int m = 0; m < 4; ++m) {
#pragma unroll
      for (int j = 0; j < 4; ++j) {
        const int rg = row0 + wr*64 + m*16 + grp*4 + j;
        const int b = rg >> 11, s5 = rg & 2047;
        const float val = (acc[m][n][j] + bb) * sc;
        int idx;
        if (mode == 2) idx = ((b*16 + h)*64 + d)*2048 + s5;
        else           idx = ((b*16 + h)*2048 + s5)*64 + d;
        dst[idx] = f2bf(val);
      }
    }
  }
}

// ---------------- O-proj GEMM: 64x128 tile, XCD-chunked, triple-buffered --------
__global__ __launch_bounds__(256) void k_gemm_o(
    const u16* __restrict__ A, const u16* __restrict__ W,
    const float* __restrict__ bias, float* __restrict__ Fo)
{
  const int bid = (int)blockIdx.x;
  const int xcd = bid & 7;
  const int i5  = bid >> 3;                    // 0..63
  const int xb_ = ((xcd >> 2) << 2) + (i5 & 3);        // 0..7
  const int yb_ = ((xcd & 3) << 4) + (i5 >> 2);        // 0..63

  __shared__ u16 lA[3][2048];
  __shared__ u16 lB[3][4096];

  const int tid  = threadIdx.x;
  const int row0 = yb_ * 64;
  const int col0 = xb_ * 128;

  const int srow = tid >> 2;
  const int sgp  = tid & 3;
  const int sgl  = sgp ^ ((srow >> 1) & 3);
  const u16* ga0 = A + (row0 + srow)      * 1024 + sgl * 8;
  const u16* gb0 = W + (col0 + srow)      * 1024 + sgl * 8;
  const u16* gb1 = W + (col0 + srow + 64) * 1024 + sgl * 8;

  const int l  = tid & 63, w = tid >> 6;
  const int wr = w >> 1,  wc = w & 1;
  const int lr = l & 15,  grp = l >> 4;
  const int sw = (lr >> 1) & 3;
  int aoff[2], boff[4];
#pragma unroll
  for (int m = 0; m < 2; ++m) aoff[m] = (wr*32 + m*16 + lr)*32 + ((grp ^ sw) * 8);
#pragma unroll
  for (int n = 0; n < 4; ++n) boff[n] = (wc*64 + n*16 + lr)*32 + ((grp ^ sw) * 8);

  floatx4 acc[2][4];
#pragma unroll
  for (int m = 0; m < 2; ++m)
#pragma unroll
    for (int n = 0; n < 4; ++n) acc[m][n] = (floatx4){0.f, 0.f, 0.f, 0.f};

#define STAGE(buf, kt_) do { \
    const int k0_ = (kt_) * 32; \
    gld16(ga0 + k0_, &lA[(buf)][tid*8]); \
    gld16(gb0 + k0_, &lB[(buf)][tid*8]); \
    gld16(gb1 + k0_, &lB[(buf)][2048 + tid*8]); \
  } while (0)

  STAGE(0, 0);
  STAGE(1, 1);
  asm volatile("s_waitcnt vmcnt(3)\ns_barrier" ::: "memory");

  for (int kt0 = 0; kt0 < 32; kt0 += 3) {
#pragma unroll
    for (int i = 0; i < 3; ++i) {
      const int kt = kt0 + i;
      if (kt >= 32) break;
      const bool st2 = (kt + 2 < 32);
      if (st2) STAGE((i + 2) % 3, kt + 2);
      short8 af[2], bf[4];
#pragma unroll
      for (int m = 0; m < 2; ++m) af[m] = *(const short8*)&lA[i][aoff[m]];
#pragma unroll
      for (int n = 0; n < 4; ++n) bf[n] = *(const short8*)&lB[i][boff[n]];
#pragma unroll
      for (int m = 0; m < 2; ++m)
#pragma unroll
        for (int n = 0; n < 4; ++n)
          acc[m][n] = __builtin_amdgcn_mfma_f32_16x16x32_bf16(af[m], bf[n], acc[m][n], 0, 0, 0);
      if (st2) WAIT_BAR_V3(); else WAIT_BAR_V0();
    }
  }
#undef STAGE

#pragma unroll
  for (int n = 0; n < 4; ++n) {
    const int cg = col0 + wc*64 + n*16 + lr;
    const float bb = bias[cg];
#pragma unroll
    for (int m = 0; m < 2; ++m) {
      const int rg = row0 + wr*32 + m*16 + grp*4;
#pragma unroll
      for (int j = 0; j < 4; ++j)
        Fo[(rg + j) * 1024 + cg] = acc[m][n][j] + bb;
    }
  }
}

// ---------------- flash attention v9: unroll-3 phases, raw v_exp ----------------
// 512 blocks x 256 thr (4 waves x 16 q). Balanced tile-pairs (31-pr, pr).
__global__ __launch_bounds__(256, 2) void k_attn(
    const u16* __restrict__ Q, const u16* __restrict__ K,
    const u16* __restrict__ V, u16* __restrict__ O)
{
  __shared__ u16 lK[3][4096];     // [64 keys][64 dk] groups-of-8 swizzled, 3 bufs
  __shared__ u16 lV[3][4096];     // [64 dk][64 keys] (V^T) swizzled, 3 bufs
  __shared__ u16 lP[4][1024];     // [wave][16 q][64 keys] (wave-private)

  const int tid = threadIdx.x;
  const int bid = (int)blockIdx.x;
  const int xcd = bid & 7, r = bid >> 3;       // 64 blocks per XCD
  const int bh = xcd * 4 + (r >> 4);           // 4 bh per XCD -> K/V L2-resident
  const int pr = r & 15;                       // pair index: tiles (31-pr, pr)

  const int l = tid & 63, w = tid >> 6;
  const int lr = l & 15, grp = l >> 4;

  const u16* Qh = Q + (size_t)bh * 2048 * 64;
  const u16* Kh = K + (size_t)bh * 2048 * 64;
  const u16* Vh = V + (size_t)bh * 64 * 2048;

  const int srow = tid >> 3, sgp = tid & 7;
  const int sgl = sgp ^ (srow & 7);
  u16* lPw = &lP[w][0];
  const int swz = lr & 7;
  const int b = bh >> 4, h = bh & 15;

#define STAGEKV(buf, kt_) do { \
    gld16(Kh + ((kt_)*64 + srow     )*64 + sgl*8, &lK[(buf)][tid*8]); \
    gld16(Kh + ((kt_)*64 + srow + 32)*64 + sgl*8, &lK[(buf)][2048 + tid*8]); \
    gld16(Vh + (srow     )*2048 + (kt_)*64 + sgl*8, &lV[(buf)][tid*8]); \
    gld16(Vh + (srow + 32)*2048 + (kt_)*64 + sgl*8, &lV[(buf)][2048 + tid*8]); \
  } while (0)

#pragma unroll
  for (int pass = 0; pass < 2; ++pass) {
    const int qt = pass ? pr : (31 - pr);
    const int qw0 = qt * 64 + w * 16;
    const int nkt = qt + 1;

    short8 qf[2];
#pragma unroll
    for (int kk = 0; kk < 2; ++kk)
      qf[kk] = *(const short8*)(Qh + (qw0 + lr)*64 + kk*32 + grp*8);

    floatx4 accO[4];               // O^T: [d=dn*16+grp*4+j][q=lr]
    float mrow = -1e30f, lrow = 0.f;   // lrow = per-lane PARTIAL (this lane's keys)
#pragma unroll
    for (int dn = 0; dn < 4; ++dn) accO[dn] = (floatx4){0.f, 0.f, 0.f, 0.f};

    STAGEKV(0, 0);
    if (nkt > 1) {
      STAGEKV(1, 1);
      asm volatile("s_waitcnt vmcnt(4)\ns_barrier" ::: "memory");
    } else {
      asm volatile("s_waitcnt vmcnt(0)\ns_barrier" ::: "memory");
    }

    for (int kt0 = 0; kt0 < nkt; kt0 += 3) {
#pragma unroll
      for (int i = 0; i < 3; ++i) {            // i == buffer index (compile-time)
        const int kt = kt0 + i;
        if (kt >= nkt) break;                  // nkt block-uniform -> barrier-safe
        const bool st2 = (kt + 2 < nkt);
        if (st2) STAGEKV((i + 2) % 3, kt + 2);
        const int kb = kt * 64;

        // S^T = K Q^T : st[n] reg j -> key = kb+n*16+grp*4+j, query = qw0+lr
        floatx4 st[4];
#pragma unroll
        for (int n = 0; n < 4; ++n) st[n] = (floatx4){0.f, 0.f, 0.f, 0.f};
#pragma unroll
        for (int n = 0; n < 4; ++n) {
          const int key = n*16 + lr;
#pragma unroll
          for (int kk = 0; kk < 2; ++kk) {
            const int gp = (kk*4 + grp) ^ (key & 7);
            short8 kf = *(const short8*)&lK[i][key*64 + gp*8];
            st[n] = __builtin_amdgcn_mfma_f32_16x16x32_bf16(kf, qf[kk], st[n], 0, 0, 0);
          }
        }

        // causal mask (only diagonal tile kt==qt is partial)
        const int lim = qw0 + lr - kb;
        if (63 > lim) {
#pragma unroll
          for (int n = 0; n < 4; ++n)
#pragma unroll
            for (int j = 0; j < 4; ++j)
              if (n*16 + grp*4 + j > lim) st[n][j] = -1e30f;
        }

        // defer-max online softmax: local max; reduce+rescale only if it grew
        float mt = st[0][0];
#pragma unroll
        for (int n = 0; n < 4; ++n)
#pragma unroll
          for (int j = 0; j < 4; ++j) mt = fmaxf(mt, st[n][j]);
        if (!__all(mt <= mrow)) {
          float mg = fmaxf(mt, __shfl_xor(mt, 16));
          mg = fmaxf(mg, __shfl_xor(mg, 32));
          const float mn = fmaxf(mrow, mg);
          const float alpha = exp2_raw(mrow - mn);
          mrow = mn;
          lrow *= alpha;
#pragma unroll
          for (int dn = 0; dn < 4; ++dn) accO[dn] *= alpha;
        }
        float ps = 0.f;
#pragma unroll
        for (int n = 0; n < 4; ++n)
#pragma unroll
          for (int j = 0; j < 4; ++j) {
            const float p = exp2_raw(st[n][j] - mrow);
            st[n][j] = p;
            ps += p;
          }
        lrow += ps;                // per-lane partial; reduced once in epilogue

        // pack P -> wave-private LDS [q][key], swizzled groups-of-8
#pragma unroll
        for (int n = 0; n < 4; ++n)
#pragma unroll
          for (int p2 = 0; p2 < 2; ++p2) {
            const unsigned pk = cvt_pk_bf16(st[n][2*p2], st[n][2*p2+1]);
            const int pg = (2*n + (grp >> 1)) ^ swz;
            ((unsigned*)lPw)[lr*32 + pg*4 + (grp & 1)*2 + p2] = pk;
          }

        asm volatile("s_waitcnt lgkmcnt(0)" ::: "memory");

        short8 pa[2];
#pragma unroll
        for (int kk = 0; kk < 2; ++kk)
          pa[kk] = *(const short8*)&lPw[lr*64 + (((kk*4 + grp) ^ swz) * 8)];

        // O^T += V^T P
#pragma unroll
        for (int dn = 0; dn < 4; ++dn) {
          const int d = dn*16 + lr;
#pragma unroll
          for (int kk = 0; kk < 2; ++kk) {
            const int gp = (kk*4 + grp) ^ (d & 7);
            short8 vf = *(const short8*)&lV[i][d*64 + gp*8];
            accO[dn] = __builtin_amdgcn_mfma_f32_16x16x32_bf16(vf, pa[kk], accO[dn], 0, 0, 0);
          }
        }

        if (st2) WAIT_BAR_V4(); else WAIT_BAR_V0();
      }
    }

    // epilogue: reduce lrow across the q-row's 4 lanes, write O^T
    float lt = lrow + __shfl_xor(lrow, 16);
    lt += __shfl_xor(lt, 32);
    const float inv = 1.0f / lt;
    const int token = b*2048 + qw0 + lr;
#pragma unroll
    for (int dn = 0; dn < 4; ++dn)
#pragma unroll
      for (int p2 = 0; p2 < 2; ++p2) {
        const unsigned pk = cvt_pk_bf16(accO[dn][2*p2] * inv, accO[dn][2*p2+1] * inv);
        *(unsigned*)&O[token*1024 + h*64 + dn*16 + grp*4 + 2*p2] = pk;
      }
  }
#undef STAGEKV
}

// ---------------- launcher ----------------
extern "C" void kernel_launch(void* const* d_in, const int* in_sizes, int n_in,
                              void* d_out, int out_size, void* d_ws, size_t ws_size,
                              hipStream_t stream) {
  const float* x  = (const float*)d_in[0];
  const float* Wq = (const float*)d_in[1];
  const float* bq = (const float*)d_in[2];
  const float* Wk = (const float*)d_in[3];
  const float* bk = (const float*)d_in[4];
  const float* Wv = (const float*)d_in[5];
  const float* bv = (const float*)d_in[6];
  const float* Wo = (const float*)d_in[7];
  const float* bo = (const float*)d_in[8];
  float* out = (float*)d_out;

  char* ws = (char*)d_ws;
  u16* xb  = (u16*)(ws + 0);          // [4096][1024] bf16
  u16* wqb = (u16*)(ws + 8388608);
  u16* wkb = (u16*)(ws + 10485760);
  u16* wvb = (u16*)(ws + 12582912);
  u16* wob = (u16*)(ws + 14680064);
  u16* Qb  = (u16*)(ws + 16777216);   // [32][2048][64]
  u16* Kb  = (u16*)(ws + 25165824);   // [32][2048][64]
  u16* Vb  = (u16*)(ws + 33554432);   // [32][64][2048]
  u16* Ab  = (u16*)(ws + 41943040);   // [4096][1024]

  k_cvt_all<<<dim3(8192), 256, 0, stream>>>(x, Wq, Wk, Wv, Wo, xb, wqb, wkb, wvb, wob);

  k_gemm_qkv<<<dim3(768), 256, 0, stream>>>(xb, wqb, wkb, wvb, bq, bk, bv, Qb, Kb, Vb);

  k_attn<<<dim3(512), 256, 0, stream>>>(Qb, Kb, Vb, Ab);

  k_gemm_o<<<dim3(512), 256, 0, stream>>>(Ab, wob, bo, out);
}

// Round 11
// 110.351 us; speedup vs baseline: 1.9507x; 1.0231x over previous
//
#include <hip/hip_runtime.h>

typedef unsigned short u16;
typedef __attribute__((ext_vector_type(8))) short short8;
typedef __attribute__((ext_vector_type(4))) float floatx4;

__device__ __forceinline__ u16 f2bf(float x){
  union { float f; unsigned u; } v; v.f = x;
  unsigned r = v.u + 0x7fffu + ((v.u >> 16) & 1u);
  return (u16)(r >> 16);
}

__device__ __forceinline__ unsigned cvt_pk_bf16(float lo, float hi){
  unsigned r;
  asm("v_cvt_pk_bf16_f32 %0, %1, %2" : "=v"(r) : "v"(lo), "v"(hi));
  return r;
}

// raw v_exp_f32: args here are always <= 0; underflow -> 0 (wanted). No OCML fixup.
__device__ __forceinline__ float exp2_raw(float x){
  float r;
  asm("v_exp_f32 %0, %1" : "=v"(r) : "v"(x));
  return r;
}

__device__ __forceinline__ void gld16(const u16* g, u16* l){
  __builtin_amdgcn_global_load_lds(
      (const __attribute__((address_space(1))) void*)g,
      (__attribute__((address_space(3))) void*)l, 16, 0, 0);
}

// counted-vmcnt barrier: previous tile's loads landed, newest stay in flight
#define WAIT_BAR_V4() asm volatile("s_waitcnt vmcnt(4) lgkmcnt(0)\ns_barrier" ::: "memory")
#define WAIT_BAR_V3() asm volatile("s_waitcnt vmcnt(3) lgkmcnt(0)\ns_barrier" ::: "memory")
#define WAIT_BAR_V0() asm volatile("s_waitcnt vmcnt(0) lgkmcnt(0)\ns_barrier" ::: "memory")

// ---------------- fused fp32 -> bf16 convert (x + 4 weights, one launch) -------
__global__ void k_cvt_all(const float* __restrict__ x,
                          const float* __restrict__ wq, const float* __restrict__ wk,
                          const float* __restrict__ wv, const float* __restrict__ wo,
                          u16* __restrict__ xb, u16* __restrict__ wqb, u16* __restrict__ wkb,
                          u16* __restrict__ wvb, u16* __restrict__ wob){
  const int i = blockIdx.x * 256 + threadIdx.x;   // float4 index, total 2097152
  const float* s; u16* d; int off;
  if (i < 1048576) { s = x; d = xb; off = i; }
  else {
    const int j = i - 1048576;
    const int wsel = j >> 18;          // 262144 f4 per weight
    off = j & 262143;
    s = (wsel==0) ? wq : (wsel==1) ? wk : (wsel==2) ? wv : wo;
    d = (wsel==0) ? wqb : (wsel==1) ? wkb : (wsel==2) ? wvb : wob;
  }
  const float4 f = ((const float4*)s)[off];
  unsigned lo = (unsigned)f2bf(f.x) | ((unsigned)f2bf(f.y) << 16);
  unsigned hi = (unsigned)f2bf(f.z) | ((unsigned)f2bf(f.w) << 16);
  ((uint2*)d)[off] = make_uint2(lo, hi);
}

// ---------------- QKV GEMM: 128x128 tile, XCD-chunked, triple-buffered ----------
// unrolled-by-3 so LDS buffer index is compile-time (imm offsets, no addr VALU)
__global__ __launch_bounds__(256) void k_gemm_qkv(
    const u16* __restrict__ A,
    const u16* __restrict__ Wq, const u16* __restrict__ Wk, const u16* __restrict__ Wv,
    const float* __restrict__ bq, const float* __restrict__ bk, const float* __restrict__ bv,
    u16* __restrict__ Qo, u16* __restrict__ Ko, u16* __restrict__ Vo)
{
  const int bid = (int)blockIdx.x;
  const int xcd = bid & 7;
  const int i5  = bid >> 3;                    // 0..95
  const int xb_ = ((xcd >> 2) << 2) + (i5 & 3);        // 0..7
  const int rest = i5 >> 2;                    // 0..23
  const int yb_ = ((xcd & 3) << 3) + (rest & 7);       // 0..31
  const int mode = rest >> 3;                  // 0..2

  const u16* W      = (mode==1) ? Wk : (mode==2) ? Wv : Wq;
  const float* bias = (mode==1) ? bk : (mode==2) ? bv : bq;

  __shared__ u16 lA[3][4096];   // [128 rows][32 k], triple-buffered
  __shared__ u16 lB[3][4096];

  const int tid  = threadIdx.x;
  const int row0 = yb_ * 128;
  const int col0 = xb_ * 128;

  const int srow = tid >> 2;
  const int sgp  = tid & 3;
  const int sgl  = sgp ^ ((srow >> 1) & 3);
  const u16* ga0 = A + (row0 + srow)      * 1024 + sgl * 8;
  const u16* ga1 = A + (row0 + srow + 64) * 1024 + sgl * 8;
  const u16* gb0 = W + (col0 + srow)      * 1024 + sgl * 8;
  const u16* gb1 = W + (col0 + srow + 64) * 1024 + sgl * 8;

  const int l  = tid & 63, w = tid >> 6;
  const int wr = w >> 1,  wc = w & 1;
  const int lr = l & 15,  grp = l >> 4;
  const int sw = (lr >> 1) & 3;
  int aoff[4], boff[4];
#pragma unroll
  for (int m = 0; m < 4; ++m) aoff[m] = (wr*64 + m*16 + lr)*32 + ((grp ^ sw) * 8);
#pragma unroll
  for (int n = 0; n < 4; ++n) boff[n] = (wc*64 + n*16 + lr)*32 + ((grp ^ sw) * 8);

  floatx4 acc[4][4];
#pragma unroll
  for (int m = 0; m < 4; ++m)
#pragma unroll
    for (int n = 0; n < 4; ++n) acc[m][n] = (floatx4){0.f, 0.f, 0.f, 0.f};

#define STAGE(buf, kt_) do { \
    const int k0_ = (kt_) * 32; \
    gld16(ga0 + k0_, &lA[(buf)][tid*8]); \
    gld16(ga1 + k0_, &lA[(buf)][2048 + tid*8]); \
    gld16(gb0 + k0_, &lB[(buf)][tid*8]); \
    gld16(gb1 + k0_, &lB[(buf)][2048 + tid*8]); \
  } while (0)

  STAGE(0, 0);
  STAGE(1, 1);
  asm volatile("s_waitcnt vmcnt(4)\ns_barrier" ::: "memory");

  for (int kt0 = 0; kt0 < 32; kt0 += 3) {
#pragma unroll
    for (int i = 0; i < 3; ++i) {              // i == buffer index (compile-time)
      const int kt = kt0 + i;
      if (kt >= 32) break;
      const bool st2 = (kt + 2 < 32);
      if (st2) STAGE((i + 2) % 3, kt + 2);
      short8 af[4], bf[4];
#pragma unroll
      for (int m = 0; m < 4; ++m) af[m] = *(const short8*)&lA[i][aoff[m]];
#pragma unroll
      for (int n = 0; n < 4; ++n) bf[n] = *(const short8*)&lB[i][boff[n]];
#pragma unroll
      for (int m = 0; m < 4; ++m)
#pragma unroll
        for (int n = 0; n < 4; ++n)
          acc[m][n] = __builtin_amdgcn_mfma_f32_16x16x32_bf16(af[m], bf[n], acc[m][n], 0, 0, 0);
      if (st2) WAIT_BAR_V4(); else WAIT_BAR_V0();
    }
  }
#undef STAGE

  const float sc = (mode == 0) ? 0.18033688011112042f : 1.0f;  // 0.125*log2(e) for Q
  u16* dst = (mode == 0) ? Qo : (mode == 1) ? Ko : Vo;
#pragma unroll
  for (int n = 0; n < 4; ++n) {
    const int cg = col0 + wc*64 + n*16 + lr;
    const float bb = bias[cg];
    const int h = cg >> 6, d = cg & 63;
#pragma unroll
    for (int m = 0; m < 4; ++m) {
#pragma unroll
      for (int j = 0; j < 4; ++j) {
        const int rg = row0 + wr*64 + m*16 + grp*4 + j;
        const int b = rg >> 11, s5 = rg & 2047;
        const float val = (acc[m][n][j] + bb) * sc;
        int idx;
        if (mode == 2) idx = ((b*16 + h)*64 + d)*2048 + s5;
        else           idx = ((b*16 + h)*2048 + s5)*64 + d;
        dst[idx] = f2bf(val);
      }
    }
  }
}

// ---------------- O-proj GEMM: 64x128 tile, XCD-chunked, triple-buffered --------
__global__ __launch_bounds__(256) void k_gemm_o(
    const u16* __restrict__ A, const u16* __restrict__ W,
    const float* __restrict__ bias, float* __restrict__ Fo)
{
  const int bid = (int)blockIdx.x;
  const int xcd = bid & 7;
  const int i5  = bid >> 3;                    // 0..63
  const int xb_ = ((xcd >> 2) << 2) + (i5 & 3);        // 0..7
  const int yb_ = ((xcd & 3) << 4) + (i5 >> 2);        // 0..63

  __shared__ u16 lA[3][2048];
  __shared__ u16 lB[3][4096];

  const int tid  = threadIdx.x;
  const int row0 = yb_ * 64;
  const int col0 = xb_ * 128;

  const int srow = tid >> 2;
  const int sgp  = tid & 3;
  const int sgl  = sgp ^ ((srow >> 1) & 3);
  const u16* ga0 = A + (row0 + srow)      * 1024 + sgl * 8;
  const u16* gb0 = W + (col0 + srow)      * 1024 + sgl * 8;
  const u16* gb1 = W + (col0 + srow + 64) * 1024 + sgl * 8;

  const int l  = tid & 63, w = tid >> 6;
  const int wr = w >> 1,  wc = w & 1;
  const int lr = l & 15,  grp = l >> 4;
  const int sw = (lr >> 1) & 3;
  int aoff[2], boff[4];
#pragma unroll
  for (int m = 0; m < 2; ++m) aoff[m] = (wr*32 + m*16 + lr)*32 + ((grp ^ sw) * 8);
#pragma unroll
  for (int n = 0; n < 4; ++n) boff[n] = (wc*64 + n*16 + lr)*32 + ((grp ^ sw) * 8);

  floatx4 acc[2][4];
#pragma unroll
  for (int m = 0; m < 2; ++m)
#pragma unroll
    for (int n = 0; n < 4; ++n) acc[m][n] = (floatx4){0.f, 0.f, 0.f, 0.f};

#define STAGE(buf, kt_) do { \
    const int k0_ = (kt_) * 32; \
    gld16(ga0 + k0_, &lA[(buf)][tid*8]); \
    gld16(gb0 + k0_, &lB[(buf)][tid*8]); \
    gld16(gb1 + k0_, &lB[(buf)][2048 + tid*8]); \
  } while (0)

  STAGE(0, 0);
  STAGE(1, 1);
  asm volatile("s_waitcnt vmcnt(3)\ns_barrier" ::: "memory");

  for (int kt0 = 0; kt0 < 32; kt0 += 3) {
#pragma unroll
    for (int i = 0; i < 3; ++i) {
      const int kt = kt0 + i;
      if (kt >= 32) break;
      const bool st2 = (kt + 2 < 32);
      if (st2) STAGE((i + 2) % 3, kt + 2);
      short8 af[2], bf[4];
#pragma unroll
      for (int m = 0; m < 2; ++m) af[m] = *(const short8*)&lA[i][aoff[m]];
#pragma unroll
      for (int n = 0; n < 4; ++n) bf[n] = *(const short8*)&lB[i][boff[n]];
#pragma unroll
      for (int m = 0; m < 2; ++m)
#pragma unroll
        for (int n = 0; n < 4; ++n)
          acc[m][n] = __builtin_amdgcn_mfma_f32_16x16x32_bf16(af[m], bf[n], acc[m][n], 0, 0, 0);
      if (st2) WAIT_BAR_V3(); else WAIT_BAR_V0();
    }
  }
#undef STAGE

#pragma unroll
  for (int n = 0; n < 4; ++n) {
    const int cg = col0 + wc*64 + n*16 + lr;
    const float bb = bias[cg];
#pragma unroll
    for (int m = 0; m < 2; ++m) {
      const int rg = row0 + wr*32 + m*16 + grp*4;
#pragma unroll
      for (int j = 0; j < 4; ++j)
        Fo[(rg + j) * 1024 + cg] = acc[m][n][j] + bb;
    }
  }
}

// ---------------- flash attention v10: 4 balanced blocks/CU ----------------
// 1024 blocks x 256 thr (4 waves x 16 q), one q-tile per block, 40KB LDS.
// CU k per XCD hosts r={k,k+32,k+64,k+96} -> qt={31-k,k,31-k,k}: 66 phases/CU.
__global__ __launch_bounds__(256, 4) void k_attn(
    const u16* __restrict__ Q, const u16* __restrict__ K,
    const u16* __restrict__ V, u16* __restrict__ O)
{
  __shared__ u16 lK[2][4096];     // [64 keys][64 dk] groups-of-8 swizzled
  __shared__ u16 lV[2][4096];     // [64 dk][64 keys] (V^T) swizzled
  __shared__ u16 lP[4][1024];     // [wave][16 q][64 keys] (wave-private)

  const int tid = threadIdx.x;
  const int bid = (int)blockIdx.x;
  const int xcd = bid & 7, r = bid >> 3;       // 128 blocks per XCD
  const int k_ = r & 31, j_ = r >> 5;          // CU index within XCD, slot 0..3
  const int bh = xcd * 4 + j_;                 // 4 bh per XCD -> K/V L2-resident
  const int qt = (j_ & 1) ? k_ : (31 - k_);    // per-CU phases: 66 for all CUs

  const int l = tid & 63, w = tid >> 6;
  const int lr = l & 15, grp = l >> 4;
  const int qw0 = qt * 64 + w * 16;
  const int nkt = qt + 1;

  const u16* Qh = Q + (size_t)bh * 2048 * 64;
  const u16* Kh = K + (size_t)bh * 2048 * 64;
  const u16* Vh = V + (size_t)bh * 64 * 2048;

  const int srow = tid >> 3, sgp = tid & 7;
  const int sgl = sgp ^ (srow & 7);
  u16* lPw = &lP[w][0];
  const int swz = lr & 7;
  const int b = bh >> 4, h = bh & 15;

#define STAGEKV(buf, kt_) do { \
    gld16(Kh + ((kt_)*64 + srow     )*64 + sgl*8, &lK[(buf)][tid*8]); \
    gld16(Kh + ((kt_)*64 + srow + 32)*64 + sgl*8, &lK[(buf)][2048 + tid*8]); \
    gld16(Vh + (srow     )*2048 + (kt_)*64 + sgl*8, &lV[(buf)][tid*8]); \
    gld16(Vh + (srow + 32)*2048 + (kt_)*64 + sgl*8, &lV[(buf)][2048 + tid*8]); \
  } while (0)

  short8 qf[2];
#pragma unroll
  for (int kk = 0; kk < 2; ++kk)
    qf[kk] = *(const short8*)(Qh + (qw0 + lr)*64 + kk*32 + grp*8);

  floatx4 accO[4];                 // O^T: [d=dn*16+grp*4+j][q=lr]
  float mrow = -1e30f, lrow = 0.f; // lrow = per-lane PARTIAL (this lane's keys)
#pragma unroll
  for (int dn = 0; dn < 4; ++dn) accO[dn] = (floatx4){0.f, 0.f, 0.f, 0.f};

  STAGEKV(0, 0);
  __syncthreads();

  for (int kt0 = 0; kt0 < nkt; kt0 += 2) {
#pragma unroll
    for (int i = 0; i < 2; ++i) {              // i == buffer index (compile-time)
      const int kt = kt0 + i;
      if (kt >= nkt) break;                    // nkt block-uniform -> barrier-safe
      if (kt + 1 < nkt) STAGEKV(i ^ 1, kt + 1);
      const int kb = kt * 64;

      // S^T = K Q^T : st[n] reg j -> key = kb+n*16+grp*4+j, query = qw0+lr
      floatx4 st[4];
#pragma unroll
      for (int n = 0; n < 4; ++n) st[n] = (floatx4){0.f, 0.f, 0.f, 0.f};
#pragma unroll
      for (int n = 0; n < 4; ++n) {
        const int key = n*16 + lr;
#pragma unroll
        for (int kk = 0; kk < 2; ++kk) {
          const int gp = (kk*4 + grp) ^ (key & 7);
          short8 kf = *(const short8*)&lK[i][key*64 + gp*8];
          st[n] = __builtin_amdgcn_mfma_f32_16x16x32_bf16(kf, qf[kk], st[n], 0, 0, 0);
        }
      }

      // causal mask (only diagonal tile kt==qt is partial)
      const int lim = qw0 + lr - kb;
      if (63 > lim) {
#pragma unroll
        for (int n = 0; n < 4; ++n)
#pragma unroll
          for (int jj = 0; jj < 4; ++jj)
            if (n*16 + grp*4 + jj > lim) st[n][jj] = -1e30f;
      }

      // defer-max online softmax: local max; reduce+rescale only if it grew
      float mt = st[0][0];
#pragma unroll
      for (int n = 0; n < 4; ++n)
#pragma unroll
        for (int jj = 0; jj < 4; ++jj) mt = fmaxf(mt, st[n][jj]);
      if (!__all(mt <= mrow)) {
        float mg = fmaxf(mt, __shfl_xor(mt, 16));
        mg = fmaxf(mg, __shfl_xor(mg, 32));
        const float mn = fmaxf(mrow, mg);
        const float alpha = exp2_raw(mrow - mn);
        mrow = mn;
        lrow *= alpha;
#pragma unroll
        for (int dn = 0; dn < 4; ++dn) accO[dn] *= alpha;
      }
      float ps = 0.f;
#pragma unroll
      for (int n = 0; n < 4; ++n)
#pragma unroll
        for (int jj = 0; jj < 4; ++jj) {
          const float p = exp2_raw(st[n][jj] - mrow);
          st[n][jj] = p;
          ps += p;
        }
      lrow += ps;                  // per-lane partial; reduced once in epilogue

      // pack P -> wave-private LDS [q][key], swizzled groups-of-8
#pragma unroll
      for (int n = 0; n < 4; ++n)
#pragma unroll
        for (int p2 = 0; p2 < 2; ++p2) {
          const unsigned pk = cvt_pk_bf16(st[n][2*p2], st[n][2*p2+1]);
          const int pg = (2*n + (grp >> 1)) ^ swz;
          ((unsigned*)lPw)[lr*32 + pg*4 + (grp & 1)*2 + p2] = pk;
        }

      asm volatile("s_waitcnt lgkmcnt(0)" ::: "memory");

      short8 pa[2];
#pragma unroll
      for (int kk = 0; kk < 2; ++kk)
        pa[kk] = *(const short8*)&lPw[lr*64 + (((kk*4 + grp) ^ swz) * 8)];

      // O^T += V^T P
#pragma unroll
      for (int dn = 0; dn < 4; ++dn) {
        const int d = dn*16 + lr;
#pragma unroll
        for (int kk = 0; kk < 2; ++kk) {
          const int gp = (kk*4 + grp) ^ (d & 7);
          short8 vf = *(const short8*)&lV[i][d*64 + gp*8];
          accO[dn] = __builtin_amdgcn_mfma_f32_16x16x32_bf16(vf, pa[kk], accO[dn], 0, 0, 0);
        }
      }
      __syncthreads();
    }
  }

  // epilogue: reduce lrow across the q-row's 4 lanes, write O^T
  float lt = lrow + __shfl_xor(lrow, 16);
  lt += __shfl_xor(lt, 32);
  const float inv = 1.0f / lt;
  const int token = b*2048 + qw0 + lr;
#pragma unroll
  for (int dn = 0; dn < 4; ++dn)
#pragma unroll
    for (int p2 = 0; p2 < 2; ++p2) {
      const unsigned pk = cvt_pk_bf16(accO[dn][2*p2] * inv, accO[dn][2*p2+1] * inv);
      *(unsigned*)&O[token*1024 + h*64 + dn*16 + grp*4 + 2*p2] = pk;
    }
#undef STAGEKV
}

// ---------------- launcher ----------------
extern "C" void kernel_launch(void* const* d_in, const int* in_sizes, int n_in,
                              void* d_out, int out_size, void* d_ws, size_t ws_size,
                              hipStream_t stream) {
  const float* x  = (const float*)d_in[0];
  const float* Wq = (const float*)d_in[1];
  const float* bq = (const float*)d_in[2];
  const float* Wk = (const float*)d_in[3];
  const float* bk = (const float*)d_in[4];
  const float* Wv = (const float*)d_in[5];
  const float* bv = (const float*)d_in[6];
  const float* Wo = (const float*)d_in[7];
  const float* bo = (const float*)d_in[8];
  float* out = (float*)d_out;

  char* ws = (char*)d_ws;
  u16* xb  = (u16*)(ws + 0);          // [4096][1024] bf16
  u16* wqb = (u16*)(ws + 8388608);
  u16* wkb = (u16*)(ws + 10485760);
  u16* wvb = (u16*)(ws + 12582912);
  u16* wob = (u16*)(ws + 14680064);
  u16* Qb  = (u16*)(ws + 16777216);   // [32][2048][64]
  u16* Kb  = (u16*)(ws + 25165824);   // [32][2048][64]
  u16* Vb  = (u16*)(ws + 33554432);   // [32][64][2048]
  u16* Ab  = (u16*)(ws + 41943040);   // [4096][1024]

  k_cvt_all<<<dim3(8192), 256, 0, stream>>>(x, Wq, Wk, Wv, Wo, xb, wqb, wkb, wvb, wob);

  k_gemm_qkv<<<dim3(768), 256, 0, stream>>>(xb, wqb, wkb, wvb, bq, bk, bv, Qb, Kb, Vb);

  k_attn<<<dim3(1024), 256, 0, stream>>>(Qb, Kb, Vb, Ab);

  k_gemm_o<<<dim3(512), 256, 0, stream>>>(Ab, wob, bo, out);
}